// Round 13
// baseline (1125.537 us; speedup 1.0000x reference)
//
#include <hip/hip_runtime.h>

#define BSH 9              // 512 nodes per dst bucket
#define BNODES 512
#define NBLK_A 256         // blocks in hist/place passes

typedef __attribute__((ext_vector_type(8))) short short8;
typedef __attribute__((ext_vector_type(4))) float floatx4;

static __device__ inline float bf2f(unsigned short u) {
    union { unsigned int i; float f; } v; v.i = ((unsigned int)u) << 16; return v.f;
}
static __device__ inline unsigned f2bf(float f) {
    union { float f; unsigned int i; } v; v.f = f;
    unsigned int x = v.i;
    return (x + 0x7FFF + ((x >> 16) & 1)) >> 16;  // RNE
}
static __device__ inline float asf(unsigned int u) {
    union { unsigned int i; float f; } v; v.i = u; return v.f;
}
static __device__ inline unsigned asu(float f) {
    union { float f; unsigned int i; } v; v.f = f; return v.i;
}

// ---------------------------------------------------------------------------
// K1: tables. root1t[64][64] f32; msg (= x1 @ W1_r, [192][64] bf16) written
// DIRECTLY in MFMA B-fragment layout.
// ---------------------------------------------------------------------------
__global__ void build_tables(const float* __restrict__ pre_w, const float* __restrict__ pre_b,
                             const float* __restrict__ w1, const float* __restrict__ root1,
                             const float* __restrict__ b1,
                             unsigned short* __restrict__ B1f, float* __restrict__ root1t) {
    int combo = blockIdx.x, j = threadIdx.x;
    __shared__ float x1s[32];
    int s = combo >> 3, c = combo & 7;
    if (j < 32) {
        float v = pre_w[s * 32 + j] + pre_w[(8 + c) * 32 + j] + pre_b[j];
        x1s[j] = v > 0.f ? v : 0.f;
    }
    __syncthreads();
    float acc = b1[j];
#pragma unroll
    for (int k = 0; k < 32; ++k) acc = fmaf(x1s[k], root1[k * 64 + j], acc);
    root1t[combo * 64 + j] = acc;
    for (int r = 0; r < 3; ++r) {
        float a = 0.f;
#pragma unroll
        for (int k = 0; k < 32; ++k) a = fmaf(x1s[k], w1[(r * 32 + k) * 64 + j], a);
        int idx = (r << 6) | combo;            // B row
        int kt = idx >> 5, i = idx & 7, lrow = (idx >> 3) & 3;
        int nt = j >> 4;
        int l = (lrow << 4) | (j & 15);
        B1f[(((nt * 6 + kt) * 64) + l) * 8 + i] = (unsigned short)f2bf(a);
    }
}

// ---------------------------------------------------------------------------
// K2: B-fragments for the [64,256] matrix [root2 | W2_0 | W2_1 | W2_2].
// ---------------------------------------------------------------------------
__global__ void prep_B2(const float* __restrict__ root2, const float* __restrict__ w2,
                        unsigned short* __restrict__ B2f) {
    int t = blockIdx.x * blockDim.x + threadIdx.x;
    if (t >= 16 * 2 * 64 * 8) return;
    int i = t & 7, l = (t >> 3) & 63, kt = (t >> 9) & 1, nt = t >> 10;
    int k = kt * 32 + ((l >> 4) * 8) + i;
    int col = nt * 16 + (l & 15);
    float v;
    if (col < 64) v = root2[k * 64 + col];
    else {
        int r = (col - 64) >> 6, wcol = (col - 64) & 63;
        v = w2[(r * 64 + k) * 64 + wcol];
    }
    B2f[t] = (unsigned short)f2bf(v);
}

// K3: combo[i] as u8
__global__ void combo_kernel(const int* __restrict__ node_x, unsigned char* __restrict__ combo, int N) {
    int i = blockIdx.x * blockDim.x + threadIdx.x;
    if (i < N) combo[i] = (unsigned char)(node_x[2 * i] * 8 + node_x[2 * i + 1]);
}

// ---------------------------------------------------------------------------
// K4 (pass A0): per-block dst-bucket histogram. hist[b*NBLK_A + blk]
// ---------------------------------------------------------------------------
__global__ void __launch_bounds__(256) hist_kernel(const int* __restrict__ ei,
                                                   int* __restrict__ hist, int E, int NB, int chunk) {
    __shared__ int lh[256];
    for (int t = threadIdx.x; t < NB; t += 256) lh[t] = 0;
    __syncthreads();
    int s = blockIdx.x * chunk, e1 = min(E, s + chunk);
    for (int e = s + threadIdx.x; e < e1; e += 256)
        atomicAdd(&lh[ei[E + e] >> BSH], 1);
    __syncthreads();
    for (int b = threadIdx.x; b < NB; b += 256) hist[b * NBLK_A + blockIdx.x] = lh[b];
}

// generic exclusive scan (3 kernels)
__global__ void scan1(const int* __restrict__ in, int* __restrict__ out,
                      int* __restrict__ bsums, int n) {
    __shared__ int s[1024];
    int i = blockIdx.x * 1024 + threadIdx.x;
    int d = (i < n) ? in[i] : 0;
    s[threadIdx.x] = d;
    __syncthreads();
    for (int off = 1; off < 1024; off <<= 1) {
        int v = (threadIdx.x >= off) ? s[threadIdx.x - off] : 0;
        __syncthreads();
        s[threadIdx.x] += v;
        __syncthreads();
    }
    if (i < n) out[i] = s[threadIdx.x] - d;
    if (threadIdx.x == 1023) bsums[blockIdx.x] = s[1023];
}
__global__ void scan2(int* __restrict__ bsums, int nb) {
    __shared__ int s[128];
    int v = (threadIdx.x < nb) ? bsums[threadIdx.x] : 0;
    s[threadIdx.x] = v;
    __syncthreads();
    for (int off = 1; off < 128; off <<= 1) {
        int u = (threadIdx.x >= off) ? s[threadIdx.x - off] : 0;
        __syncthreads();
        s[threadIdx.x] += u;
        __syncthreads();
    }
    if (threadIdx.x < nb) bsums[threadIdx.x] = s[threadIdx.x] - v;
}
__global__ void scan3(int* __restrict__ out, const int* __restrict__ bsums, int n) {
    int i = blockIdx.x * 1024 + threadIdx.x;
    if (i < n) out[i] += bsums[blockIdx.x];
}

// ---------------------------------------------------------------------------
// K5 (pass A1): place edges into dst-buckets. staged = dloc<<19 | rel<<17 | src
// ---------------------------------------------------------------------------
__global__ void __launch_bounds__(256) place_kernel(const int* __restrict__ ei, const int* __restrict__ et,
                                                    const int* __restrict__ off, unsigned* __restrict__ staged,
                                                    int E, int NB, int chunk) {
    __shared__ int lh[256];
    for (int t = threadIdx.x; t < NB; t += 256) lh[t] = 0;
    __syncthreads();
    int s = blockIdx.x * chunk, e1 = min(E, s + chunk);
    for (int e = s + threadIdx.x; e < e1; e += 256) {
        int d = ei[E + e];
        int b = d >> BSH;
        int lr = atomicAdd(&lh[b], 1);
        int pos = off[b * NBLK_A + blockIdx.x] + lr;
        staged[pos] = ((unsigned)(d & (BNODES - 1)) << 19) | ((unsigned)et[e] << 17) | (unsigned)ei[e];
    }
}

// ---------------------------------------------------------------------------
// K6 (pass B): finalize into whole-node x4-padded CSR with per-edge
// precomputed weight w = 1/cnt(dst,rel).
//   edges2[e] = { nl<<26 | (rel*N+src)*16 (uint2 row offset into Y), asu(w) }
//   edges1[e] = f2bf(w)<<16 | (node%64)<<8 | (rel*64+combo)   (pads: w=0)
//   base1[i], plen[i]; sentinel base1[N] = end of padded edge array
// Bucket capacity = raw + 3*BNODES.
// ---------------------------------------------------------------------------
__global__ void __launch_bounds__(256) finalize_kernel(
        const unsigned* __restrict__ staged, const int* __restrict__ off,
        const unsigned char* __restrict__ combo,
        unsigned* __restrict__ edges1, uint2* __restrict__ edges2,
        int* __restrict__ base1, unsigned short* __restrict__ plen,
        int E, int N, int NB) {
    __shared__ int lrel[BNODES * 3];   // per-(node,rel) counts (stay counts)
    __shared__ float lwf[BNODES * 3];  // 1/count
    __shared__ int lcnt[BNODES];       // placement cursors
    __shared__ int part[256];
    int blk = blockIdx.x;
    int d0 = blk * BNODES;
    int nn = min(BNODES, N - d0);
    int estart = off[blk * NBLK_A];
    int eend = (blk == NB - 1) ? E : off[(blk + 1) * NBLK_A];
    int ebase = estart + blk * (BNODES * 3);   // padded-capacity base
    for (int t = threadIdx.x; t < BNODES * 3; t += 256) lrel[t] = 0;
    __syncthreads();
    for (int e = estart + threadIdx.x; e < eend; e += 256) {
        unsigned p = staged[e];
        atomicAdd(&lrel[(p >> 19) * 3 + ((p >> 17) & 3)], 1);
    }
    __syncthreads();
    for (int j = threadIdx.x; j < BNODES * 3; j += 256) {
        int c = lrel[j];
        lwf[j] = c ? 1.f / (float)c : 0.f;
    }
    // padded exclusive scan over whole-node lengths (2 nodes/thread)
    int t = threadIdx.x;
    int n0 = 2 * t, n1 = 2 * t + 1;
    int ct0 = lrel[n0 * 3] + lrel[n0 * 3 + 1] + lrel[n0 * 3 + 2];
    int ct1 = lrel[n1 * 3] + lrel[n1 * 3 + 1] + lrel[n1 * 3 + 2];
    int pl0 = (ct0 + 3) & ~3, pl1 = (ct1 + 3) & ~3;
    int sum = pl0 + pl1;
    part[t] = sum;
    __syncthreads();
    for (int o = 1; o < 256; o <<= 1) {
        int u = (t >= o) ? part[t - o] : 0;
        __syncthreads();
        part[t] += u;
        __syncthreads();
    }
    int run = ebase + part[t] - sum;
    lcnt[n0] = run;
    lcnt[n1] = run + pl0;
    if (n0 < nn) { base1[d0 + n0] = run;       plen[d0 + n0] = (unsigned short)pl0; }
    if (n1 < nn) { base1[d0 + n1] = run + pl0; plen[d0 + n1] = (unsigned short)pl1; }
    if (blk == NB - 1 && t == 255) base1[N] = ebase + part[255];   // sentinel
    __syncthreads();
    for (int e = estart + threadIdx.x; e < eend; e += 256) {
        unsigned p = staged[e];
        int dloc = p >> 19;
        unsigned rel = (p >> 17) & 3;
        unsigned src = p & 0x1FFFF;
        float w = lwf[dloc * 3 + rel];
        int slot = atomicAdd(&lcnt[dloc], 1);
        uint2 e2;
        e2.x = ((unsigned)(dloc & 63) << 26) | ((rel * (unsigned)N + src) * 16u);
        e2.y = asu(w);
        edges2[slot] = e2;
        edges1[slot] = (f2bf(w) << 16) | ((unsigned)(dloc & 63) << 8)
                     | (rel << 6) | (unsigned)combo[src];
    }
    __syncthreads();
    for (int n = threadIdx.x; n < nn; n += 256) {
        int ct = lrel[n * 3] + lrel[n * 3 + 1] + lrel[n * 3 + 2];
        int need = ((ct + 3) & ~3) - ct;          // 0..3 pads, w = 0
        int cur = lcnt[n];
        for (int k = 0; k < need; ++k) {
            uint2 z; z.x = (unsigned)(n & 63) << 26; z.y = 0u;   // w=0
            edges2[cur + k] = z;
            edges1[cur + k] = 0u;        // w=0 -> contributes nothing
        }
    }
}

// ---------------------------------------------------------------------------
// K7: conv1 as count-matrix MFMA. Block = 64 nodes.
// ---------------------------------------------------------------------------
#define CSTR 196
__global__ void __launch_bounds__(256) conv1_mfma(
        const unsigned* __restrict__ edges1, const int* __restrict__ base1,
        const unsigned short* __restrict__ B1f, const float* __restrict__ root1t,
        const unsigned char* __restrict__ combo, unsigned short* __restrict__ h1, int N) {
    __shared__ float Cs[64 * CSTR];
    for (int t = threadIdx.x; t < 64 * CSTR; t += 256) Cs[t] = 0.f;
    __syncthreads();
    int g0 = blockIdx.x * 64;
    int gEnd = min(g0 + 64, N);
    int estart = base1[g0], eend = base1[gEnd];
    for (int e = estart + threadIdx.x; e < eend; e += 256) {
        unsigned ew = edges1[e];
        float wt = asf(ew & 0xFFFF0000u);        // bf16 weight in high bits
        int nl = (ew >> 8) & 63;
        int idx = ew & 255u;
        atomicAdd(&Cs[nl * CSTR + idx], wt);
    }
    __syncthreads();
    int lane = threadIdx.x & 63;
    int w0 = threadIdx.x >> 6;
    int node0 = g0 + 16 * w0;
    if (node0 >= N) return;
    int m = lane & 15, kg = lane >> 4;
    const float* cr = &Cs[(16 * w0 + m) * CSTR];
    short8 a[6];
#pragma unroll
    for (int kt = 0; kt < 6; ++kt) {
        float4 ca = *(const float4*)(cr + kt * 32 + kg * 8);
        float4 cb = *(const float4*)(cr + kt * 32 + kg * 8 + 4);
        short8 av;
        av[0] = (short)f2bf(ca.x); av[1] = (short)f2bf(ca.y);
        av[2] = (short)f2bf(ca.z); av[3] = (short)f2bf(ca.w);
        av[4] = (short)f2bf(cb.x); av[5] = (short)f2bf(cb.y);
        av[6] = (short)f2bf(cb.z); av[7] = (short)f2bf(cb.w);
        a[kt] = av;
    }
#pragma unroll
    for (int nt = 0; nt < 4; ++nt) {
        floatx4 c = {0.f, 0.f, 0.f, 0.f};
#pragma unroll
        for (int kt = 0; kt < 6; ++kt) {
            short8 b = *(const short8*)(B1f + ((nt * 6 + kt) * 64 + lane) * 8);
            c = __builtin_amdgcn_mfma_f32_16x16x32_bf16(a[kt], b, c, 0, 0, 0);
        }
#pragma unroll
        for (int q = 0; q < 4; ++q) {
            int node = node0 + kg * 4 + q;
            if (node < N) {
                float v = c[q] + root1t[(int)combo[node] * 64 + nt * 16 + m];
                v = v > 0.f ? v : 0.f;
                h1[(size_t)node * 64 + nt * 16 + m] = (unsigned short)f2bf(v);
            }
        }
    }
}

// ---------------------------------------------------------------------------
// K8: gemm_Y. [16,64]@[64,256] MFMA per wave: cols 0..63 -> R = h1@root2+b2,
// cols 64..255 -> Y_r = h1@W2_r. All bf16 out.
// ---------------------------------------------------------------------------
__global__ void __launch_bounds__(256) gemm_Y(
        const unsigned short* __restrict__ h1, const unsigned short* __restrict__ B2f,
        const float* __restrict__ b2, unsigned short* __restrict__ Rb,
        unsigned short* __restrict__ Y, int N) {
    int g = blockIdx.x * 4 + (threadIdx.x >> 6);
    int node0 = g * 16;
    if (node0 >= N) return;
    int lane = threadIdx.x & 63;
    int m = lane & 15, kg = lane >> 4;
    short8 a[2];
#pragma unroll
    for (int kt = 0; kt < 2; ++kt)
        a[kt] = *(const short8*)(h1 + (size_t)(node0 + m) * 64 + kt * 32 + kg * 8);
#pragma unroll
    for (int nt = 0; nt < 16; ++nt) {
        floatx4 c = {0.f, 0.f, 0.f, 0.f};
#pragma unroll
        for (int kt = 0; kt < 2; ++kt) {
            short8 b = *(const short8*)(B2f + ((nt * 2 + kt) * 64 + lane) * 8);
            c = __builtin_amdgcn_mfma_f32_16x16x32_bf16(a[kt], b, c, 0, 0, 0);
        }
        if (nt < 4) {
            int col = nt * 16 + m;
            float bias = b2[col];
#pragma unroll
            for (int q = 0; q < 4; ++q) {
                int node = node0 + kg * 4 + q;
                if (node < N) Rb[(size_t)node * 64 + col] = (unsigned short)f2bf(c[q] + bias);
            }
        } else {
            int r = (nt - 4) >> 2;
            int ycol = ((nt - 4) & 3) * 16 + m;
#pragma unroll
            for (int q = 0; q < 4; ++q) {
                int node = node0 + kg * 4 + q;
                if (node < N)
                    Y[((size_t)r * N + node) * 64 + ycol] = (unsigned short)f2bf(c[q]);
            }
        }
    }
}

// ---------------------------------------------------------------------------
// K9: conv2 as block-range edge-parallel stream + LDS f32 accumulate.
// Block = 64 dst nodes. 16 quarter-waves stream the block's edge range:
// per edge 1 coalesced edge load + 1 independent Y-row load (128B via 16
// lanes x uint2) + 4 LDS atomicAdds. No per-node loops/chains/reductions.
// Epilogue: h2 = agg + R (pre-relu).
// ---------------------------------------------------------------------------
__global__ void __launch_bounds__(256) conv2_lds(
        const uint2* __restrict__ edges2, const int* __restrict__ base1,
        const uint2* __restrict__ Yu2, const uint2* __restrict__ Ru2,
        uint2* __restrict__ h2u2, int N) {
    __shared__ float agg[64 * 64];   // 16 KB
    for (int t = threadIdx.x; t < 64 * 64; t += 256) agg[t] = 0.f;
    __syncthreads();
    int g0 = blockIdx.x * 64;
    int gEnd = min(g0 + 64, N);
    int estart = base1[g0], eend = base1[gEnd];
    int l16 = threadIdx.x & 15;             // dims 4*l16 .. 4*l16+3
    int grp = threadIdx.x >> 4;             // 16 edge-groups per block
    for (int e = estart + grp; e < eend; e += 16) {
        uint2 ed = edges2[e];
        float wt = asf(ed.y);
        unsigned nl = ed.x >> 26;
        unsigned off = ed.x & 0x03FFFFFFu;
        uint2 v = Yu2[(size_t)off + l16];
        float* ap = &agg[nl * 64 + l16 * 4];
        atomicAdd(ap + 0, wt * asf(v.x << 16));
        atomicAdd(ap + 1, wt * asf(v.x & 0xFFFF0000u));
        atomicAdd(ap + 2, wt * asf(v.y << 16));
        atomicAdd(ap + 3, wt * asf(v.y & 0xFFFF0000u));
    }
    __syncthreads();
    for (int t = threadIdx.x; t < 64 * 16; t += 256) {
        int nl = t >> 4;
        int node = g0 + nl;
        if (node < N) {
            int du = t & 15;                // uint2 index: dims 4*du..4*du+3
            const float* ap = &agg[nl * 64 + du * 4];
            uint2 rb = Ru2[(size_t)node * 16 + du];
            float f0 = ap[0] + asf(rb.x << 16);
            float f1 = ap[1] + asf(rb.x & 0xFFFF0000u);
            float f2 = ap[2] + asf(rb.y << 16);
            float f3 = ap[3] + asf(rb.y & 0xFFFF0000u);
            uint2 o;
            o.x = f2bf(f0) | (f2bf(f1) << 16);
            o.y = f2bf(f2) | (f2bf(f3) << 16);
            h2u2[(size_t)node * 16 + du] = o;
        }
    }
}

// ---------------------------------------------------------------------------
// K10: mean-pool (sorted batch -> binary search) + classifier; relu folded.
// ---------------------------------------------------------------------------
__global__ void __launch_bounds__(64) pool_cls(
        const unsigned short* __restrict__ h2, const int* __restrict__ batch,
        const float* __restrict__ cls_w, const float* __restrict__ cls_b,
        float* __restrict__ out, int N, int G) {
    int g = blockIdx.x, lane = threadIdx.x;
    auto lb = [&](int key) {
        int lo = 0, hi = N;
        while (lo < hi) { int mid = (lo + hi) >> 1; if (batch[mid] < key) lo = mid + 1; else hi = mid; }
        return lo;
    };
    int start = lb(g), end = lb(g + 1);
    float sum = 0.f;
    for (int i = start; i < end; ++i) {
        float v = bf2f(h2[(size_t)i * 64 + lane]);
        sum += v > 0.f ? v : 0.f;
    }
    int cntn = end - start;
    float pooled = sum / (float)(cntn > 0 ? cntn : 1);
    __shared__ float ps[64];
    ps[lane] = pooled;
    __syncthreads();
    if (lane < 10) {
        float o = cls_b[lane];
#pragma unroll
        for (int j = 0; j < 64; ++j) o = fmaf(ps[j], cls_w[j * 10 + lane], o);
        out[g * 10 + lane] = o;
    }
}

// ---------------------------------------------------------------------------
extern "C" void kernel_launch(void* const* d_in, const int* in_sizes, int n_in,
                              void* d_out, int out_size, void* d_ws, size_t ws_size,
                              hipStream_t stream) {
    const int*   node_x = (const int*)d_in[0];
    const int*   ei     = (const int*)d_in[1];
    const int*   et     = (const int*)d_in[2];
    const int*   batch  = (const int*)d_in[3];
    const float* pre_w  = (const float*)d_in[4];
    const float* pre_b  = (const float*)d_in[5];
    const float* w1     = (const float*)d_in[6];
    const float* root1  = (const float*)d_in[7];
    const float* b1     = (const float*)d_in[8];
    const float* w2     = (const float*)d_in[9];
    const float* root2  = (const float*)d_in[10];
    const float* b2     = (const float*)d_in[11];
    const float* cls_w  = (const float*)d_in[12];
    const float* cls_b  = (const float*)d_in[13];
    float* out = (float*)d_out;

    int N = in_sizes[0] / 2;
    int E = in_sizes[1] / 2;
    int G = out_size / 10;

    int NB = (N + BNODES - 1) >> BSH;
    int chunk = (E + NBLK_A - 1) / NBLK_A;
    int nh = NB * NBLK_A;
    int nscan = (nh + 1023) / 1024;
    int EP = E + NB * BNODES * 3;      // whole-node pads (<=3/node)

    char* ws = (char*)d_ws;
    size_t off_b = 0;
    auto alloc = [&](size_t bytes) {
        void* p = ws + off_b;
        off_b = (off_b + bytes + 255) & ~(size_t)255;
        return p;
    };
    unsigned short* B1f    = (unsigned short*)alloc(4 * 6 * 64 * 8 * sizeof(short));
    float*          root1t = (float*)alloc(64 * 64 * sizeof(float));
    unsigned short* B2f    = (unsigned short*)alloc(16 * 2 * 64 * 8 * sizeof(short));
    unsigned char*  combo  = (unsigned char*)alloc((size_t)N + 64);
    int*            hist   = (int*)alloc((size_t)nh * sizeof(int));
    int*            hoff   = (int*)alloc((size_t)nh * sizeof(int));
    int*            bsums  = (int*)alloc(128 * sizeof(int));
    unsigned*       staged = (unsigned*)alloc((size_t)E * sizeof(unsigned));
    unsigned*       edges1 = (unsigned*)alloc((size_t)EP * sizeof(unsigned));
    uint2*          edges2 = (uint2*)alloc(((size_t)EP + 16) * sizeof(uint2));
    int*            base1  = (int*)alloc(((size_t)N + 8) * sizeof(int));
    unsigned short* plen   = (unsigned short*)alloc(((size_t)N + 8) * sizeof(short));
    unsigned short* h1     = (unsigned short*)alloc((size_t)(N + 16) * 64 * sizeof(short));
    unsigned short* Rb     = (unsigned short*)alloc((size_t)N * 64 * sizeof(short));
    unsigned short* Y      = (unsigned short*)alloc((size_t)3 * N * 64 * sizeof(short));
    unsigned short* h2     = (unsigned short*)alloc((size_t)N * 64 * sizeof(short));

    build_tables<<<64, 64, 0, stream>>>(pre_w, pre_b, w1, root1, b1, B1f, root1t);
    prep_B2<<<64, 256, 0, stream>>>(root2, w2, B2f);
    combo_kernel<<<(N + 255) / 256, 256, 0, stream>>>(node_x, combo, N);

    hist_kernel<<<NBLK_A, 256, 0, stream>>>(ei, hist, E, NB, chunk);
    scan1<<<nscan, 1024, 0, stream>>>(hist, hoff, bsums, nh);
    scan2<<<1, 128, 0, stream>>>(bsums, nscan);
    scan3<<<nscan, 1024, 0, stream>>>(hoff, bsums, nh);
    place_kernel<<<NBLK_A, 256, 0, stream>>>(ei, et, hoff, staged, E, NB, chunk);
    finalize_kernel<<<NB, 256, 0, stream>>>(staged, hoff, combo, edges1, edges2,
                                            base1, plen, E, N, NB);

    conv1_mfma<<<(N + 63) / 64, 256, 0, stream>>>(edges1, base1, B1f, root1t, combo, h1, N);
    gemm_Y<<<((N + 15) / 16 + 3) / 4, 256, 0, stream>>>(h1, B2f, b2, Rb, Y, N);
    conv2_lds<<<(N + 63) / 64, 256, 0, stream>>>(edges2, base1, (const uint2*)Y,
                                                 (const uint2*)Rb, (uint2*)h2, N);
    pool_cls<<<G, 64, 0, stream>>>(h2, batch, cls_w, cls_b, out, N, G);
}

// Round 14
// 208.224 us; speedup vs baseline: 5.4054x; 5.4054x over previous
//
#include <hip/hip_runtime.h>

#define BSH 9              // 512 nodes per dst bucket
#define BNODES 512
#define NBLK_A 256         // blocks in hist/place passes

typedef __attribute__((ext_vector_type(8))) short short8;
typedef __attribute__((ext_vector_type(4))) float floatx4;

static __device__ inline float bf2f(unsigned short u) {
    union { unsigned int i; float f; } v; v.i = ((unsigned int)u) << 16; return v.f;
}
static __device__ inline unsigned f2bf(float f) {
    union { float f; unsigned int i; } v; v.f = f;
    unsigned int x = v.i;
    return (x + 0x7FFF + ((x >> 16) & 1)) >> 16;  // RNE
}
static __device__ inline float asf(unsigned int u) {
    union { unsigned int i; float f; } v; v.i = u; return v.f;
}
static __device__ inline unsigned asu(float f) {
    union { float f; unsigned int i; } v; v.f = f; return v.i;
}

// ---------------------------------------------------------------------------
// K1: tables. root1t[64][64] f32; msg (= x1 @ W1_r, [192][64] bf16) written
// DIRECTLY in MFMA B-fragment layout.
// ---------------------------------------------------------------------------
__global__ void build_tables(const float* __restrict__ pre_w, const float* __restrict__ pre_b,
                             const float* __restrict__ w1, const float* __restrict__ root1,
                             const float* __restrict__ b1,
                             unsigned short* __restrict__ B1f, float* __restrict__ root1t) {
    int combo = blockIdx.x, j = threadIdx.x;
    __shared__ float x1s[32];
    int s = combo >> 3, c = combo & 7;
    if (j < 32) {
        float v = pre_w[s * 32 + j] + pre_w[(8 + c) * 32 + j] + pre_b[j];
        x1s[j] = v > 0.f ? v : 0.f;
    }
    __syncthreads();
    float acc = b1[j];
#pragma unroll
    for (int k = 0; k < 32; ++k) acc = fmaf(x1s[k], root1[k * 64 + j], acc);
    root1t[combo * 64 + j] = acc;
    for (int r = 0; r < 3; ++r) {
        float a = 0.f;
#pragma unroll
        for (int k = 0; k < 32; ++k) a = fmaf(x1s[k], w1[(r * 32 + k) * 64 + j], a);
        int idx = (r << 6) | combo;            // B row
        int kt = idx >> 5, i = idx & 7, lrow = (idx >> 3) & 3;
        int nt = j >> 4;
        int l = (lrow << 4) | (j & 15);
        B1f[(((nt * 6 + kt) * 64) + l) * 8 + i] = (unsigned short)f2bf(a);
    }
}

// ---------------------------------------------------------------------------
// K2: B-fragments for the [64,256] matrix [root2 | W2_0 | W2_1 | W2_2].
// ---------------------------------------------------------------------------
__global__ void prep_B2(const float* __restrict__ root2, const float* __restrict__ w2,
                        unsigned short* __restrict__ B2f) {
    int t = blockIdx.x * blockDim.x + threadIdx.x;
    if (t >= 16 * 2 * 64 * 8) return;
    int i = t & 7, l = (t >> 3) & 63, kt = (t >> 9) & 1, nt = t >> 10;
    int k = kt * 32 + ((l >> 4) * 8) + i;
    int col = nt * 16 + (l & 15);
    float v;
    if (col < 64) v = root2[k * 64 + col];
    else {
        int r = (col - 64) >> 6, wcol = (col - 64) & 63;
        v = w2[(r * 64 + k) * 64 + wcol];
    }
    B2f[t] = (unsigned short)f2bf(v);
}

// K3: combo[i] as u8
__global__ void combo_kernel(const int* __restrict__ node_x, unsigned char* __restrict__ combo, int N) {
    int i = blockIdx.x * blockDim.x + threadIdx.x;
    if (i < N) combo[i] = (unsigned char)(node_x[2 * i] * 8 + node_x[2 * i + 1]);
}

// ---------------------------------------------------------------------------
// K4 (pass A0): per-block dst-bucket histogram. hist[b*NBLK_A + blk]
// ---------------------------------------------------------------------------
__global__ void __launch_bounds__(256) hist_kernel(const int* __restrict__ ei,
                                                   int* __restrict__ hist, int E, int NB, int chunk) {
    __shared__ int lh[256];
    for (int t = threadIdx.x; t < NB; t += 256) lh[t] = 0;
    __syncthreads();
    int s = blockIdx.x * chunk, e1 = min(E, s + chunk);
    for (int e = s + threadIdx.x; e < e1; e += 256)
        atomicAdd(&lh[ei[E + e] >> BSH], 1);
    __syncthreads();
    for (int b = threadIdx.x; b < NB; b += 256) hist[b * NBLK_A + blockIdx.x] = lh[b];
}

// generic exclusive scan (3 kernels)
__global__ void scan1(const int* __restrict__ in, int* __restrict__ out,
                      int* __restrict__ bsums, int n) {
    __shared__ int s[1024];
    int i = blockIdx.x * 1024 + threadIdx.x;
    int d = (i < n) ? in[i] : 0;
    s[threadIdx.x] = d;
    __syncthreads();
    for (int off = 1; off < 1024; off <<= 1) {
        int v = (threadIdx.x >= off) ? s[threadIdx.x - off] : 0;
        __syncthreads();
        s[threadIdx.x] += v;
        __syncthreads();
    }
    if (i < n) out[i] = s[threadIdx.x] - d;
    if (threadIdx.x == 1023) bsums[blockIdx.x] = s[1023];
}
__global__ void scan2(int* __restrict__ bsums, int nb) {
    __shared__ int s[128];
    int v = (threadIdx.x < nb) ? bsums[threadIdx.x] : 0;
    s[threadIdx.x] = v;
    __syncthreads();
    for (int off = 1; off < 128; off <<= 1) {
        int u = (threadIdx.x >= off) ? s[threadIdx.x - off] : 0;
        __syncthreads();
        s[threadIdx.x] += u;
        __syncthreads();
    }
    if (threadIdx.x < nb) bsums[threadIdx.x] = s[threadIdx.x] - v;
}
__global__ void scan3(int* __restrict__ out, const int* __restrict__ bsums, int n) {
    int i = blockIdx.x * 1024 + threadIdx.x;
    if (i < n) out[i] += bsums[blockIdx.x];
}

// ---------------------------------------------------------------------------
// K5 (pass A1): place edges into dst-buckets. staged = dloc<<19 | rel<<17 | src
// ---------------------------------------------------------------------------
__global__ void __launch_bounds__(256) place_kernel(const int* __restrict__ ei, const int* __restrict__ et,
                                                    const int* __restrict__ off, unsigned* __restrict__ staged,
                                                    int E, int NB, int chunk) {
    __shared__ int lh[256];
    for (int t = threadIdx.x; t < NB; t += 256) lh[t] = 0;
    __syncthreads();
    int s = blockIdx.x * chunk, e1 = min(E, s + chunk);
    for (int e = s + threadIdx.x; e < e1; e += 256) {
        int d = ei[E + e];
        int b = d >> BSH;
        int lr = atomicAdd(&lh[b], 1);
        int pos = off[b * NBLK_A + blockIdx.x] + lr;
        staged[pos] = ((unsigned)(d & (BNODES - 1)) << 19) | ((unsigned)et[e] << 17) | (unsigned)ei[e];
    }
}

// ---------------------------------------------------------------------------
// K6 (pass B): finalize into whole-node x4-padded CSR with per-edge
// precomputed weight w = 1/cnt(dst,rel).
//   edges2[e] = { (rel*N+src)*16 (uint2 row offset into Y), asu(w) }
//   edges1[e] = f2bf(w)<<16 | (node%64)<<8 | (rel*64+combo)   (pads: w=0)
//   base1[i], plen[i]; sentinel base1[N] = end of padded edge array
// Bucket capacity = raw + 3*BNODES.
// ---------------------------------------------------------------------------
__global__ void __launch_bounds__(256) finalize_kernel(
        const unsigned* __restrict__ staged, const int* __restrict__ off,
        const unsigned char* __restrict__ combo,
        unsigned* __restrict__ edges1, uint2* __restrict__ edges2,
        int* __restrict__ base1, unsigned short* __restrict__ plen,
        int E, int N, int NB) {
    __shared__ int lrel[BNODES * 3];   // per-(node,rel) counts (stay counts)
    __shared__ float lwf[BNODES * 3];  // 1/count
    __shared__ int lcnt[BNODES];       // placement cursors
    __shared__ int part[256];
    int blk = blockIdx.x;
    int d0 = blk * BNODES;
    int nn = min(BNODES, N - d0);
    int estart = off[blk * NBLK_A];
    int eend = (blk == NB - 1) ? E : off[(blk + 1) * NBLK_A];
    int ebase = estart + blk * (BNODES * 3);   // padded-capacity base
    for (int t = threadIdx.x; t < BNODES * 3; t += 256) lrel[t] = 0;
    __syncthreads();
    for (int e = estart + threadIdx.x; e < eend; e += 256) {
        unsigned p = staged[e];
        atomicAdd(&lrel[(p >> 19) * 3 + ((p >> 17) & 3)], 1);
    }
    __syncthreads();
    for (int j = threadIdx.x; j < BNODES * 3; j += 256) {
        int c = lrel[j];
        lwf[j] = c ? 1.f / (float)c : 0.f;
    }
    // padded exclusive scan over whole-node lengths (2 nodes/thread)
    int t = threadIdx.x;
    int n0 = 2 * t, n1 = 2 * t + 1;
    int ct0 = lrel[n0 * 3] + lrel[n0 * 3 + 1] + lrel[n0 * 3 + 2];
    int ct1 = lrel[n1 * 3] + lrel[n1 * 3 + 1] + lrel[n1 * 3 + 2];
    int pl0 = (ct0 + 3) & ~3, pl1 = (ct1 + 3) & ~3;
    int sum = pl0 + pl1;
    part[t] = sum;
    __syncthreads();
    for (int o = 1; o < 256; o <<= 1) {
        int u = (t >= o) ? part[t - o] : 0;
        __syncthreads();
        part[t] += u;
        __syncthreads();
    }
    int run = ebase + part[t] - sum;
    lcnt[n0] = run;
    lcnt[n1] = run + pl0;
    if (n0 < nn) { base1[d0 + n0] = run;       plen[d0 + n0] = (unsigned short)pl0; }
    if (n1 < nn) { base1[d0 + n1] = run + pl0; plen[d0 + n1] = (unsigned short)pl1; }
    if (blk == NB - 1 && t == 255) base1[N] = ebase + part[255];   // sentinel
    __syncthreads();
    for (int e = estart + threadIdx.x; e < eend; e += 256) {
        unsigned p = staged[e];
        int dloc = p >> 19;
        unsigned rel = (p >> 17) & 3;
        unsigned src = p & 0x1FFFF;
        float w = lwf[dloc * 3 + rel];
        int slot = atomicAdd(&lcnt[dloc], 1);
        uint2 e2;
        e2.x = (rel * (unsigned)N + src) * 16u;
        e2.y = asu(w);
        edges2[slot] = e2;
        edges1[slot] = (f2bf(w) << 16) | ((unsigned)(dloc & 63) << 8)
                     | (rel << 6) | (unsigned)combo[src];
    }
    __syncthreads();
    for (int n = threadIdx.x; n < nn; n += 256) {
        int ct = lrel[n * 3] + lrel[n * 3 + 1] + lrel[n * 3 + 2];
        int need = ((ct + 3) & ~3) - ct;          // 0..3 pads, w = 0
        int cur = lcnt[n];
        for (int k = 0; k < need; ++k) {
            uint2 z; z.x = 0u; z.y = 0u;
            edges2[cur + k] = z;
            edges1[cur + k] = 0u;        // w=0 -> contributes nothing
        }
    }
}

// ---------------------------------------------------------------------------
// K7: conv1 as count-matrix MFMA. Block = 64 nodes.
// ---------------------------------------------------------------------------
#define CSTR 196
__global__ void __launch_bounds__(256) conv1_mfma(
        const unsigned* __restrict__ edges1, const int* __restrict__ base1,
        const unsigned short* __restrict__ B1f, const float* __restrict__ root1t,
        const unsigned char* __restrict__ combo, unsigned short* __restrict__ h1, int N) {
    __shared__ float Cs[64 * CSTR];
    for (int t = threadIdx.x; t < 64 * CSTR; t += 256) Cs[t] = 0.f;
    __syncthreads();
    int g0 = blockIdx.x * 64;
    int gEnd = min(g0 + 64, N);
    int estart = base1[g0], eend = base1[gEnd];
    for (int e = estart + threadIdx.x; e < eend; e += 256) {
        unsigned ew = edges1[e];
        float wt = asf(ew & 0xFFFF0000u);        // bf16 weight in high bits
        int nl = (ew >> 8) & 63;
        int idx = ew & 255u;
        atomicAdd(&Cs[nl * CSTR + idx], wt);
    }
    __syncthreads();
    int lane = threadIdx.x & 63;
    int w0 = threadIdx.x >> 6;
    int node0 = g0 + 16 * w0;
    if (node0 >= N) return;
    int m = lane & 15, kg = lane >> 4;
    const float* cr = &Cs[(16 * w0 + m) * CSTR];
    short8 a[6];
#pragma unroll
    for (int kt = 0; kt < 6; ++kt) {
        float4 ca = *(const float4*)(cr + kt * 32 + kg * 8);
        float4 cb = *(const float4*)(cr + kt * 32 + kg * 8 + 4);
        short8 av;
        av[0] = (short)f2bf(ca.x); av[1] = (short)f2bf(ca.y);
        av[2] = (short)f2bf(ca.z); av[3] = (short)f2bf(ca.w);
        av[4] = (short)f2bf(cb.x); av[5] = (short)f2bf(cb.y);
        av[6] = (short)f2bf(cb.z); av[7] = (short)f2bf(cb.w);
        a[kt] = av;
    }
#pragma unroll
    for (int nt = 0; nt < 4; ++nt) {
        floatx4 c = {0.f, 0.f, 0.f, 0.f};
#pragma unroll
        for (int kt = 0; kt < 6; ++kt) {
            short8 b = *(const short8*)(B1f + ((nt * 6 + kt) * 64 + lane) * 8);
            c = __builtin_amdgcn_mfma_f32_16x16x32_bf16(a[kt], b, c, 0, 0, 0);
        }
#pragma unroll
        for (int q = 0; q < 4; ++q) {
            int node = node0 + kg * 4 + q;
            if (node < N) {
                float v = c[q] + root1t[(int)combo[node] * 64 + nt * 16 + m];
                v = v > 0.f ? v : 0.f;
                h1[(size_t)node * 64 + nt * 16 + m] = (unsigned short)f2bf(v);
            }
        }
    }
}

// ---------------------------------------------------------------------------
// K8: gemm_Y. [16,64]@[64,256] MFMA per wave: cols 0..63 -> R = h1@root2+b2,
// cols 64..255 -> Y_r = h1@W2_r. All bf16 out.
// ---------------------------------------------------------------------------
__global__ void __launch_bounds__(256) gemm_Y(
        const unsigned short* __restrict__ h1, const unsigned short* __restrict__ B2f,
        const float* __restrict__ b2, unsigned short* __restrict__ Rb,
        unsigned short* __restrict__ Y, int N) {
    int g = blockIdx.x * 4 + (threadIdx.x >> 6);
    int node0 = g * 16;
    if (node0 >= N) return;
    int lane = threadIdx.x & 63;
    int m = lane & 15, kg = lane >> 4;
    short8 a[2];
#pragma unroll
    for (int kt = 0; kt < 2; ++kt)
        a[kt] = *(const short8*)(h1 + (size_t)(node0 + m) * 64 + kt * 32 + kg * 8);
#pragma unroll
    for (int nt = 0; nt < 16; ++nt) {
        floatx4 c = {0.f, 0.f, 0.f, 0.f};
#pragma unroll
        for (int kt = 0; kt < 2; ++kt) {
            short8 b = *(const short8*)(B2f + ((nt * 2 + kt) * 64 + lane) * 8);
            c = __builtin_amdgcn_mfma_f32_16x16x32_bf16(a[kt], b, c, 0, 0, 0);
        }
        if (nt < 4) {
            int col = nt * 16 + m;
            float bias = b2[col];
#pragma unroll
            for (int q = 0; q < 4; ++q) {
                int node = node0 + kg * 4 + q;
                if (node < N) Rb[(size_t)node * 64 + col] = (unsigned short)f2bf(c[q] + bias);
            }
        } else {
            int r = (nt - 4) >> 2;
            int ycol = ((nt - 4) & 3) * 16 + m;
#pragma unroll
            for (int q = 0; q < 4; ++q) {
                int node = node0 + kg * 4 + q;
                if (node < N)
                    Y[((size_t)r * N + node) * 64 + ycol] = (unsigned short)f2bf(c[q]);
            }
        }
    }
}

// ---------------------------------------------------------------------------
// K9: conv2 gather, UNROLL x2. Wave per node; quarter-wave per edge; main
// loop issues 2 edge-word loads + 2 Y-row loads (8 edges/wave/iter) to
// double memory-level parallelism. h2 = R + sum (pre-relu).
// ---------------------------------------------------------------------------
__global__ void __launch_bounds__(256) conv2_gather(
        const uint2* __restrict__ edges2, const int* __restrict__ base1,
        const unsigned short* __restrict__ plen, const uint2* __restrict__ Yu2,
        const uint2* __restrict__ Ru2, uint2* __restrict__ h2u2, int N) {
    int i = blockIdx.x * 4 + (threadIdx.x >> 6);
    if (i >= N) return;
    int lane = threadIdx.x & 63;
    int l16 = lane & 15, q = lane >> 4;
    int s = base1[i];
    int L = plen[i];
    float f0 = 0.f, f1 = 0.f, f2 = 0.f, f3 = 0.f;
    int t2 = 0;
    for (; t2 + 8 <= L; t2 += 8) {
        uint2 ea = edges2[s + t2 + q];
        uint2 eb = edges2[s + t2 + 4 + q];
        uint2 va = Yu2[(size_t)ea.x + l16];
        uint2 vb = Yu2[(size_t)eb.x + l16];
        float wa = asf(ea.y), wb = asf(eb.y);
        f0 = fmaf(wa, asf(va.x << 16), f0);
        f1 = fmaf(wa, asf(va.x & 0xFFFF0000u), f1);
        f2 = fmaf(wa, asf(va.y << 16), f2);
        f3 = fmaf(wa, asf(va.y & 0xFFFF0000u), f3);
        f0 = fmaf(wb, asf(vb.x << 16), f0);
        f1 = fmaf(wb, asf(vb.x & 0xFFFF0000u), f1);
        f2 = fmaf(wb, asf(vb.y << 16), f2);
        f3 = fmaf(wb, asf(vb.y & 0xFFFF0000u), f3);
    }
    if (t2 < L) {
        uint2 ea = edges2[s + t2 + q];
        uint2 va = Yu2[(size_t)ea.x + l16];
        float wa = asf(ea.y);
        f0 = fmaf(wa, asf(va.x << 16), f0);
        f1 = fmaf(wa, asf(va.x & 0xFFFF0000u), f1);
        f2 = fmaf(wa, asf(va.y << 16), f2);
        f3 = fmaf(wa, asf(va.y & 0xFFFF0000u), f3);
    }
    f0 += __shfl_xor(f0, 16); f0 += __shfl_xor(f0, 32);
    f1 += __shfl_xor(f1, 16); f1 += __shfl_xor(f1, 32);
    f2 += __shfl_xor(f2, 16); f2 += __shfl_xor(f2, 32);
    f3 += __shfl_xor(f3, 16); f3 += __shfl_xor(f3, 32);
    if (q == 0) {
        uint2 rb = Ru2[(size_t)i * 16 + l16];
        f0 += asf(rb.x << 16);
        f1 += asf(rb.x & 0xFFFF0000u);
        f2 += asf(rb.y << 16);
        f3 += asf(rb.y & 0xFFFF0000u);
        uint2 o;
        o.x = f2bf(f0) | (f2bf(f1) << 16);
        o.y = f2bf(f2) | (f2bf(f3) << 16);
        h2u2[(size_t)i * 16 + l16] = o;
    }
}

// ---------------------------------------------------------------------------
// K10: mean-pool (sorted batch -> binary search) + classifier; relu folded.
// ---------------------------------------------------------------------------
__global__ void __launch_bounds__(64) pool_cls(
        const unsigned short* __restrict__ h2, const int* __restrict__ batch,
        const float* __restrict__ cls_w, const float* __restrict__ cls_b,
        float* __restrict__ out, int N, int G) {
    int g = blockIdx.x, lane = threadIdx.x;
    auto lb = [&](int key) {
        int lo = 0, hi = N;
        while (lo < hi) { int mid = (lo + hi) >> 1; if (batch[mid] < key) lo = mid + 1; else hi = mid; }
        return lo;
    };
    int start = lb(g), end = lb(g + 1);
    float sum = 0.f;
    for (int i = start; i < end; ++i) {
        float v = bf2f(h2[(size_t)i * 64 + lane]);
        sum += v > 0.f ? v : 0.f;
    }
    int cntn = end - start;
    float pooled = sum / (float)(cntn > 0 ? cntn : 1);
    __shared__ float ps[64];
    ps[lane] = pooled;
    __syncthreads();
    if (lane < 10) {
        float o = cls_b[lane];
#pragma unroll
        for (int j = 0; j < 64; ++j) o = fmaf(ps[j], cls_w[j * 10 + lane], o);
        out[g * 10 + lane] = o;
    }
}

// ---------------------------------------------------------------------------
extern "C" void kernel_launch(void* const* d_in, const int* in_sizes, int n_in,
                              void* d_out, int out_size, void* d_ws, size_t ws_size,
                              hipStream_t stream) {
    const int*   node_x = (const int*)d_in[0];
    const int*   ei     = (const int*)d_in[1];
    const int*   et     = (const int*)d_in[2];
    const int*   batch  = (const int*)d_in[3];
    const float* pre_w  = (const float*)d_in[4];
    const float* pre_b  = (const float*)d_in[5];
    const float* w1     = (const float*)d_in[6];
    const float* root1  = (const float*)d_in[7];
    const float* b1     = (const float*)d_in[8];
    const float* w2     = (const float*)d_in[9];
    const float* root2  = (const float*)d_in[10];
    const float* b2     = (const float*)d_in[11];
    const float* cls_w  = (const float*)d_in[12];
    const float* cls_b  = (const float*)d_in[13];
    float* out = (float*)d_out;

    int N = in_sizes[0] / 2;
    int E = in_sizes[1] / 2;
    int G = out_size / 10;

    int NB = (N + BNODES - 1) >> BSH;
    int chunk = (E + NBLK_A - 1) / NBLK_A;
    int nh = NB * NBLK_A;
    int nscan = (nh + 1023) / 1024;
    int EP = E + NB * BNODES * 3;      // whole-node pads (<=3/node)

    char* ws = (char*)d_ws;
    size_t off_b = 0;
    auto alloc = [&](size_t bytes) {
        void* p = ws + off_b;
        off_b = (off_b + bytes + 255) & ~(size_t)255;
        return p;
    };
    unsigned short* B1f    = (unsigned short*)alloc(4 * 6 * 64 * 8 * sizeof(short));
    float*          root1t = (float*)alloc(64 * 64 * sizeof(float));
    unsigned short* B2f    = (unsigned short*)alloc(16 * 2 * 64 * 8 * sizeof(short));
    unsigned char*  combo  = (unsigned char*)alloc((size_t)N + 64);
    int*            hist   = (int*)alloc((size_t)nh * sizeof(int));
    int*            hoff   = (int*)alloc((size_t)nh * sizeof(int));
    int*            bsums  = (int*)alloc(128 * sizeof(int));
    unsigned*       staged = (unsigned*)alloc((size_t)E * sizeof(unsigned));
    unsigned*       edges1 = (unsigned*)alloc((size_t)EP * sizeof(unsigned));
    uint2*          edges2 = (uint2*)alloc(((size_t)EP + 16) * sizeof(uint2));
    int*            base1  = (int*)alloc(((size_t)N + 8) * sizeof(int));
    unsigned short* plen   = (unsigned short*)alloc(((size_t)N + 8) * sizeof(short));
    unsigned short* h1     = (unsigned short*)alloc((size_t)(N + 16) * 64 * sizeof(short));
    unsigned short* Rb     = (unsigned short*)alloc((size_t)N * 64 * sizeof(short));
    unsigned short* Y      = (unsigned short*)alloc((size_t)3 * N * 64 * sizeof(short));
    unsigned short* h2     = (unsigned short*)alloc((size_t)N * 64 * sizeof(short));

    build_tables<<<64, 64, 0, stream>>>(pre_w, pre_b, w1, root1, b1, B1f, root1t);
    prep_B2<<<64, 256, 0, stream>>>(root2, w2, B2f);
    combo_kernel<<<(N + 255) / 256, 256, 0, stream>>>(node_x, combo, N);

    hist_kernel<<<NBLK_A, 256, 0, stream>>>(ei, hist, E, NB, chunk);
    scan1<<<nscan, 1024, 0, stream>>>(hist, hoff, bsums, nh);
    scan2<<<1, 128, 0, stream>>>(bsums, nscan);
    scan3<<<nscan, 1024, 0, stream>>>(hoff, bsums, nh);
    place_kernel<<<NBLK_A, 256, 0, stream>>>(ei, et, hoff, staged, E, NB, chunk);
    finalize_kernel<<<NB, 256, 0, stream>>>(staged, hoff, combo, edges1, edges2,
                                            base1, plen, E, N, NB);

    conv1_mfma<<<(N + 63) / 64, 256, 0, stream>>>(edges1, base1, B1f, root1t, combo, h1, N);
    gemm_Y<<<((N + 15) / 16 + 3) / 4, 256, 0, stream>>>(h1, B2f, b2, Rb, Y, N);
    conv2_gather<<<(N + 3) / 4, 256, 0, stream>>>(edges2, base1, plen, (const uint2*)Y,
                                                  (const uint2*)Rb, (uint2*)h2, N);
    pool_cls<<<G, 64, 0, stream>>>(h2, batch, cls_w, cls_b, out, N, G);
}

// Round 15
// 174.353 us; speedup vs baseline: 6.4555x; 1.1943x over previous
//
#include <hip/hip_runtime.h>

#define BSH 9              // 512 nodes per dst bucket
#define BNODES 512
#define NBLK_A 256         // blocks in hist/place passes

typedef __attribute__((ext_vector_type(8))) short short8;
typedef __attribute__((ext_vector_type(4))) float floatx4;

static __device__ inline float bf2f(unsigned short u) {
    union { unsigned int i; float f; } v; v.i = ((unsigned int)u) << 16; return v.f;
}
static __device__ inline unsigned f2bf(float f) {
    union { float f; unsigned int i; } v; v.f = f;
    unsigned int x = v.i;
    return (x + 0x7FFF + ((x >> 16) & 1)) >> 16;  // RNE
}
static __device__ inline float asf(unsigned int u) {
    union { unsigned int i; float f; } v; v.i = u; return v.f;
}
static __device__ inline unsigned asu(float f) {
    union { float f; unsigned int i; } v; v.f = f; return v.i;
}

// ---------------------------------------------------------------------------
// K1 (merged setup): per-combo tables + B2 fragments.
//   threads 0..63: root1t[64][64] f32 and B1f (msg in MFMA B-frag layout)
//   all 256:       B2f slice (64 blocks x 256 = 16384 elements exactly)
// ---------------------------------------------------------------------------
__global__ void __launch_bounds__(256) setup_kernel(
        const float* __restrict__ pre_w, const float* __restrict__ pre_b,
        const float* __restrict__ w1, const float* __restrict__ root1,
        const float* __restrict__ b1, const float* __restrict__ root2,
        const float* __restrict__ w2,
        unsigned short* __restrict__ B1f, float* __restrict__ root1t,
        unsigned short* __restrict__ B2f) {
    int combo = blockIdx.x;
    int t = threadIdx.x;
    __shared__ float x1s[32];
    if (t < 32) {
        int s = combo >> 3, c = combo & 7;
        float v = pre_w[s * 32 + t] + pre_w[(8 + c) * 32 + t] + pre_b[t];
        x1s[t] = v > 0.f ? v : 0.f;
    }
    __syncthreads();
    if (t < 64) {
        int j = t;
        float acc = b1[j];
#pragma unroll
        for (int k = 0; k < 32; ++k) acc = fmaf(x1s[k], root1[k * 64 + j], acc);
        root1t[combo * 64 + j] = acc;
        for (int r = 0; r < 3; ++r) {
            float a = 0.f;
#pragma unroll
            for (int k = 0; k < 32; ++k) a = fmaf(x1s[k], w1[(r * 32 + k) * 64 + j], a);
            int idx = (r << 6) | combo;            // B row
            int kt = idx >> 5, i = idx & 7, lrow = (idx >> 3) & 3;
            int nt = j >> 4;
            int l = (lrow << 4) | (j & 15);
            B1f[(((nt * 6 + kt) * 64) + l) * 8 + i] = (unsigned short)f2bf(a);
        }
    }
    {   // B2f: [root2 | W2_0 | W2_1 | W2_2] fragments
        int tt = combo * 256 + t;                  // 0 .. 16383
        int i = tt & 7, l = (tt >> 3) & 63, kt = (tt >> 9) & 1, nt = tt >> 10;
        int k = kt * 32 + ((l >> 4) * 8) + i;
        int col = nt * 16 + (l & 15);
        float v;
        if (col < 64) v = root2[k * 64 + col];
        else {
            int r = (col - 64) >> 6, wcol = (col - 64) & 63;
            v = w2[(r * 64 + k) * 64 + wcol];
        }
        B2f[tt] = (unsigned short)f2bf(v);
    }
}

// K3: combo[i] as u8
__global__ void combo_kernel(const int* __restrict__ node_x, unsigned char* __restrict__ combo, int N) {
    int i = blockIdx.x * blockDim.x + threadIdx.x;
    if (i < N) combo[i] = (unsigned char)(node_x[2 * i] * 8 + node_x[2 * i + 1]);
}

// ---------------------------------------------------------------------------
// K4 (pass A0): per-block dst-bucket histogram. hist[b*NBLK_A + blk]
// ---------------------------------------------------------------------------
__global__ void __launch_bounds__(256) hist_kernel(const int* __restrict__ ei,
                                                   int* __restrict__ hist, int E, int NB, int chunk) {
    __shared__ int lh[256];
    for (int t = threadIdx.x; t < NB; t += 256) lh[t] = 0;
    __syncthreads();
    int s = blockIdx.x * chunk, e1 = min(E, s + chunk);
    for (int e = s + threadIdx.x; e < e1; e += 256)
        atomicAdd(&lh[ei[E + e] >> BSH], 1);
    __syncthreads();
    for (int b = threadIdx.x; b < NB; b += 256) hist[b * NBLK_A + blockIdx.x] = lh[b];
}

// generic exclusive scan (3 kernels)
__global__ void scan1(const int* __restrict__ in, int* __restrict__ out,
                      int* __restrict__ bsums, int n) {
    __shared__ int s[1024];
    int i = blockIdx.x * 1024 + threadIdx.x;
    int d = (i < n) ? in[i] : 0;
    s[threadIdx.x] = d;
    __syncthreads();
    for (int off = 1; off < 1024; off <<= 1) {
        int v = (threadIdx.x >= off) ? s[threadIdx.x - off] : 0;
        __syncthreads();
        s[threadIdx.x] += v;
        __syncthreads();
    }
    if (i < n) out[i] = s[threadIdx.x] - d;
    if (threadIdx.x == 1023) bsums[blockIdx.x] = s[1023];
}
__global__ void scan2(int* __restrict__ bsums, int nb) {
    __shared__ int s[128];
    int v = (threadIdx.x < nb) ? bsums[threadIdx.x] : 0;
    s[threadIdx.x] = v;
    __syncthreads();
    for (int off = 1; off < 128; off <<= 1) {
        int u = (threadIdx.x >= off) ? s[threadIdx.x - off] : 0;
        __syncthreads();
        s[threadIdx.x] += u;
        __syncthreads();
    }
    if (threadIdx.x < nb) bsums[threadIdx.x] = s[threadIdx.x] - v;
}
__global__ void scan3(int* __restrict__ out, const int* __restrict__ bsums, int n) {
    int i = blockIdx.x * 1024 + threadIdx.x;
    if (i < n) out[i] += bsums[blockIdx.x];
}

// ---------------------------------------------------------------------------
// K5 (pass A1): place edges into dst-buckets. staged = dloc<<19 | rel<<17 | src
// ---------------------------------------------------------------------------
__global__ void __launch_bounds__(256) place_kernel(const int* __restrict__ ei, const int* __restrict__ et,
                                                    const int* __restrict__ off, unsigned* __restrict__ staged,
                                                    int E, int NB, int chunk) {
    __shared__ int lh[256];
    for (int t = threadIdx.x; t < NB; t += 256) lh[t] = 0;
    __syncthreads();
    int s = blockIdx.x * chunk, e1 = min(E, s + chunk);
    for (int e = s + threadIdx.x; e < e1; e += 256) {
        int d = ei[E + e];
        int b = d >> BSH;
        int lr = atomicAdd(&lh[b], 1);
        int pos = off[b * NBLK_A + blockIdx.x] + lr;
        staged[pos] = ((unsigned)(d & (BNODES - 1)) << 19) | ((unsigned)et[e] << 17) | (unsigned)ei[e];
    }
}

// ---------------------------------------------------------------------------
// K6 (pass B): finalize into whole-node x4-padded CSR with per-edge
// precomputed weight w = 1/cnt(dst,rel).
//   edges2[e] = { (rel*N+src)*16 (uint2 row offset into Y), asu(w) }
//   edges1[e] = f2bf(w)<<16 | (node%64)<<8 | (rel*64+combo)   (pads: w=0)
//   base1[i], plen[i]; sentinel base1[N] = end of padded edge array
// Bucket capacity = raw + 3*BNODES.
// ---------------------------------------------------------------------------
__global__ void __launch_bounds__(256) finalize_kernel(
        const unsigned* __restrict__ staged, const int* __restrict__ off,
        const unsigned char* __restrict__ combo,
        unsigned* __restrict__ edges1, uint2* __restrict__ edges2,
        int* __restrict__ base1, unsigned short* __restrict__ plen,
        int E, int N, int NB) {
    __shared__ int lrel[BNODES * 3];   // per-(node,rel) counts (stay counts)
    __shared__ float lwf[BNODES * 3];  // 1/count
    __shared__ int lcnt[BNODES];       // placement cursors
    __shared__ int part[256];
    int blk = blockIdx.x;
    int d0 = blk * BNODES;
    int nn = min(BNODES, N - d0);
    int estart = off[blk * NBLK_A];
    int eend = (blk == NB - 1) ? E : off[(blk + 1) * NBLK_A];
    int ebase = estart + blk * (BNODES * 3);   // padded-capacity base
    for (int t = threadIdx.x; t < BNODES * 3; t += 256) lrel[t] = 0;
    __syncthreads();
    for (int e = estart + threadIdx.x; e < eend; e += 256) {
        unsigned p = staged[e];
        atomicAdd(&lrel[(p >> 19) * 3 + ((p >> 17) & 3)], 1);
    }
    __syncthreads();
    for (int j = threadIdx.x; j < BNODES * 3; j += 256) {
        int c = lrel[j];
        lwf[j] = c ? 1.f / (float)c : 0.f;
    }
    // padded exclusive scan over whole-node lengths (2 nodes/thread)
    int t = threadIdx.x;
    int n0 = 2 * t, n1 = 2 * t + 1;
    int ct0 = lrel[n0 * 3] + lrel[n0 * 3 + 1] + lrel[n0 * 3 + 2];
    int ct1 = lrel[n1 * 3] + lrel[n1 * 3 + 1] + lrel[n1 * 3 + 2];
    int pl0 = (ct0 + 3) & ~3, pl1 = (ct1 + 3) & ~3;
    int sum = pl0 + pl1;
    part[t] = sum;
    __syncthreads();
    for (int o = 1; o < 256; o <<= 1) {
        int u = (t >= o) ? part[t - o] : 0;
        __syncthreads();
        part[t] += u;
        __syncthreads();
    }
    int run = ebase + part[t] - sum;
    lcnt[n0] = run;
    lcnt[n1] = run + pl0;
    if (n0 < nn) { base1[d0 + n0] = run;       plen[d0 + n0] = (unsigned short)pl0; }
    if (n1 < nn) { base1[d0 + n1] = run + pl0; plen[d0 + n1] = (unsigned short)pl1; }
    if (blk == NB - 1 && t == 255) base1[N] = ebase + part[255];   // sentinel
    __syncthreads();
    for (int e = estart + threadIdx.x; e < eend; e += 256) {
        unsigned p = staged[e];
        int dloc = p >> 19;
        unsigned rel = (p >> 17) & 3;
        unsigned src = p & 0x1FFFF;
        float w = lwf[dloc * 3 + rel];
        int slot = atomicAdd(&lcnt[dloc], 1);
        uint2 e2;
        e2.x = (rel * (unsigned)N + src) * 16u;
        e2.y = asu(w);
        edges2[slot] = e2;
        edges1[slot] = (f2bf(w) << 16) | ((unsigned)(dloc & 63) << 8)
                     | (rel << 6) | (unsigned)combo[src];
    }
    __syncthreads();
    for (int n = threadIdx.x; n < nn; n += 256) {
        int ct = lrel[n * 3] + lrel[n * 3 + 1] + lrel[n * 3 + 2];
        int need = ((ct + 3) & ~3) - ct;          // 0..3 pads, w = 0
        int cur = lcnt[n];
        for (int k = 0; k < need; ++k) {
            uint2 z; z.x = 0u; z.y = 0u;
            edges2[cur + k] = z;
            edges1[cur + k] = 0u;        // w=0 -> contributes nothing
        }
    }
}

// ---------------------------------------------------------------------------
// K7: conv1 as count-matrix MFMA. Block = 64 nodes.
// ---------------------------------------------------------------------------
#define CSTR 196
__global__ void __launch_bounds__(256) conv1_mfma(
        const unsigned* __restrict__ edges1, const int* __restrict__ base1,
        const unsigned short* __restrict__ B1f, const float* __restrict__ root1t,
        const unsigned char* __restrict__ combo, unsigned short* __restrict__ h1, int N) {
    __shared__ float Cs[64 * CSTR];
    for (int t = threadIdx.x; t < 64 * CSTR; t += 256) Cs[t] = 0.f;
    __syncthreads();
    int g0 = blockIdx.x * 64;
    int gEnd = min(g0 + 64, N);
    int estart = base1[g0], eend = base1[gEnd];
    for (int e = estart + threadIdx.x; e < eend; e += 256) {
        unsigned ew = edges1[e];
        float wt = asf(ew & 0xFFFF0000u);        // bf16 weight in high bits
        int nl = (ew >> 8) & 63;
        int idx = ew & 255u;
        atomicAdd(&Cs[nl * CSTR + idx], wt);
    }
    __syncthreads();
    int lane = threadIdx.x & 63;
    int w0 = threadIdx.x >> 6;
    int node0 = g0 + 16 * w0;
    if (node0 >= N) return;
    int m = lane & 15, kg = lane >> 4;
    const float* cr = &Cs[(16 * w0 + m) * CSTR];
    short8 a[6];
#pragma unroll
    for (int kt = 0; kt < 6; ++kt) {
        float4 ca = *(const float4*)(cr + kt * 32 + kg * 8);
        float4 cb = *(const float4*)(cr + kt * 32 + kg * 8 + 4);
        short8 av;
        av[0] = (short)f2bf(ca.x); av[1] = (short)f2bf(ca.y);
        av[2] = (short)f2bf(ca.z); av[3] = (short)f2bf(ca.w);
        av[4] = (short)f2bf(cb.x); av[5] = (short)f2bf(cb.y);
        av[6] = (short)f2bf(cb.z); av[7] = (short)f2bf(cb.w);
        a[kt] = av;
    }
#pragma unroll
    for (int nt = 0; nt < 4; ++nt) {
        floatx4 c = {0.f, 0.f, 0.f, 0.f};
#pragma unroll
        for (int kt = 0; kt < 6; ++kt) {
            short8 b = *(const short8*)(B1f + ((nt * 6 + kt) * 64 + lane) * 8);
            c = __builtin_amdgcn_mfma_f32_16x16x32_bf16(a[kt], b, c, 0, 0, 0);
        }
#pragma unroll
        for (int q = 0; q < 4; ++q) {
            int node = node0 + kg * 4 + q;
            if (node < N) {
                float v = c[q] + root1t[(int)combo[node] * 64 + nt * 16 + m];
                v = v > 0.f ? v : 0.f;
                h1[(size_t)node * 64 + nt * 16 + m] = (unsigned short)f2bf(v);
            }
        }
    }
}

// ---------------------------------------------------------------------------
// K8: gemm_Y. [16,64]@[64,256] MFMA per wave: cols 0..63 -> R = h1@root2+b2,
// cols 64..255 -> Y_r = h1@W2_r. All bf16 out.
// ---------------------------------------------------------------------------
__global__ void __launch_bounds__(256) gemm_Y(
        const unsigned short* __restrict__ h1, const unsigned short* __restrict__ B2f,
        const float* __restrict__ b2, unsigned short* __restrict__ Rb,
        unsigned short* __restrict__ Y, int N) {
    int g = blockIdx.x * 4 + (threadIdx.x >> 6);
    int node0 = g * 16;
    if (node0 >= N) return;
    int lane = threadIdx.x & 63;
    int m = lane & 15, kg = lane >> 4;
    short8 a[2];
#pragma unroll
    for (int kt = 0; kt < 2; ++kt)
        a[kt] = *(const short8*)(h1 + (size_t)(node0 + m) * 64 + kt * 32 + kg * 8);
#pragma unroll
    for (int nt = 0; nt < 16; ++nt) {
        floatx4 c = {0.f, 0.f, 0.f, 0.f};
#pragma unroll
        for (int kt = 0; kt < 2; ++kt) {
            short8 b = *(const short8*)(B2f + ((nt * 2 + kt) * 64 + lane) * 8);
            c = __builtin_amdgcn_mfma_f32_16x16x32_bf16(a[kt], b, c, 0, 0, 0);
        }
        if (nt < 4) {
            int col = nt * 16 + m;
            float bias = b2[col];
#pragma unroll
            for (int q = 0; q < 4; ++q) {
                int node = node0 + kg * 4 + q;
                if (node < N) Rb[(size_t)node * 64 + col] = (unsigned short)f2bf(c[q] + bias);
            }
        } else {
            int r = (nt - 4) >> 2;
            int ycol = ((nt - 4) & 3) * 16 + m;
#pragma unroll
            for (int q = 0; q < 4; ++q) {
                int node = node0 + kg * 4 + q;
                if (node < N)
                    Y[((size_t)r * N + node) * 64 + ycol] = (unsigned short)f2bf(c[q]);
            }
        }
    }
}

// ---------------------------------------------------------------------------
// K9: conv2 gather, HALF-WAVE per node. 8 lanes x uint4 (16B) per edge ->
// 4 edges/iter per node; unroll x2 -> per wave 4 edge-word + 4 Y-row loads
// in flight across 2 independent nodes. h2 = R + sum (pre-relu).
// ---------------------------------------------------------------------------
__global__ void __launch_bounds__(256) conv2_gather(
        const uint2* __restrict__ edges2, const int* __restrict__ base1,
        const unsigned short* __restrict__ plen, const uint4* __restrict__ Yu4,
        const uint4* __restrict__ Ru4, uint4* __restrict__ h2u4, int N) {
    int i = blockIdx.x * 8 + (threadIdx.x >> 5);   // node per 32-lane half
    if (i >= N) return;
    int l5 = threadIdx.x & 31;
    int el = l5 >> 3;        // edge slot 0..3
    int dl = l5 & 7;         // dim octet 0..7 (8 bf16 each)
    int s = base1[i];
    int L = plen[i];
    float f0 = 0.f, f1 = 0.f, f2 = 0.f, f3 = 0.f;
    float f4 = 0.f, f5 = 0.f, f6 = 0.f, f7 = 0.f;
    int t2 = 0;
    for (; t2 + 8 <= L; t2 += 8) {
        uint2 ea = edges2[s + t2 + el];
        uint2 eb = edges2[s + t2 + 4 + el];
        uint4 va = Yu4[(size_t)(ea.x >> 1) + dl];
        uint4 vb = Yu4[(size_t)(eb.x >> 1) + dl];
        float wa = asf(ea.y), wb = asf(eb.y);
        f0 = fmaf(wa, asf(va.x << 16), f0);
        f1 = fmaf(wa, asf(va.x & 0xFFFF0000u), f1);
        f2 = fmaf(wa, asf(va.y << 16), f2);
        f3 = fmaf(wa, asf(va.y & 0xFFFF0000u), f3);
        f4 = fmaf(wa, asf(va.z << 16), f4);
        f5 = fmaf(wa, asf(va.z & 0xFFFF0000u), f5);
        f6 = fmaf(wa, asf(va.w << 16), f6);
        f7 = fmaf(wa, asf(va.w & 0xFFFF0000u), f7);
        f0 = fmaf(wb, asf(vb.x << 16), f0);
        f1 = fmaf(wb, asf(vb.x & 0xFFFF0000u), f1);
        f2 = fmaf(wb, asf(vb.y << 16), f2);
        f3 = fmaf(wb, asf(vb.y & 0xFFFF0000u), f3);
        f4 = fmaf(wb, asf(vb.z << 16), f4);
        f5 = fmaf(wb, asf(vb.z & 0xFFFF0000u), f5);
        f6 = fmaf(wb, asf(vb.w << 16), f6);
        f7 = fmaf(wb, asf(vb.w & 0xFFFF0000u), f7);
    }
    if (t2 < L) {
        uint2 ea = edges2[s + t2 + el];
        uint4 va = Yu4[(size_t)(ea.x >> 1) + dl];
        float wa = asf(ea.y);
        f0 = fmaf(wa, asf(va.x << 16), f0);
        f1 = fmaf(wa, asf(va.x & 0xFFFF0000u), f1);
        f2 = fmaf(wa, asf(va.y << 16), f2);
        f3 = fmaf(wa, asf(va.y & 0xFFFF0000u), f3);
        f4 = fmaf(wa, asf(va.z << 16), f4);
        f5 = fmaf(wa, asf(va.z & 0xFFFF0000u), f5);
        f6 = fmaf(wa, asf(va.w << 16), f6);
        f7 = fmaf(wa, asf(va.w & 0xFFFF0000u), f7);
    }
    // reduce across the 4 edge slots (lanes +-8, +-16 within the half)
    f0 += __shfl_xor(f0, 8); f0 += __shfl_xor(f0, 16);
    f1 += __shfl_xor(f1, 8); f1 += __shfl_xor(f1, 16);
    f2 += __shfl_xor(f2, 8); f2 += __shfl_xor(f2, 16);
    f3 += __shfl_xor(f3, 8); f3 += __shfl_xor(f3, 16);
    f4 += __shfl_xor(f4, 8); f4 += __shfl_xor(f4, 16);
    f5 += __shfl_xor(f5, 8); f5 += __shfl_xor(f5, 16);
    f6 += __shfl_xor(f6, 8); f6 += __shfl_xor(f6, 16);
    f7 += __shfl_xor(f7, 8); f7 += __shfl_xor(f7, 16);
    if (el == 0) {
        uint4 rb = Ru4[(size_t)i * 8 + dl];
        f0 += asf(rb.x << 16);
        f1 += asf(rb.x & 0xFFFF0000u);
        f2 += asf(rb.y << 16);
        f3 += asf(rb.y & 0xFFFF0000u);
        f4 += asf(rb.z << 16);
        f5 += asf(rb.z & 0xFFFF0000u);
        f6 += asf(rb.w << 16);
        f7 += asf(rb.w & 0xFFFF0000u);
        uint4 o;
        o.x = f2bf(f0) | (f2bf(f1) << 16);
        o.y = f2bf(f2) | (f2bf(f3) << 16);
        o.z = f2bf(f4) | (f2bf(f5) << 16);
        o.w = f2bf(f6) | (f2bf(f7) << 16);
        h2u4[(size_t)i * 8 + dl] = o;
    }
}

// ---------------------------------------------------------------------------
// K10: mean-pool + classifier, 4 waves per graph (rows split across waves).
// ---------------------------------------------------------------------------
__global__ void __launch_bounds__(256) pool_cls(
        const unsigned short* __restrict__ h2, const int* __restrict__ batch,
        const float* __restrict__ cls_w, const float* __restrict__ cls_b,
        float* __restrict__ out, int N, int G) {
    int g = blockIdx.x;
    int lane = threadIdx.x & 63, w = threadIdx.x >> 6;
    auto lb = [&](int key) {
        int lo = 0, hi = N;
        while (lo < hi) { int mid = (lo + hi) >> 1; if (batch[mid] < key) lo = mid + 1; else hi = mid; }
        return lo;
    };
    int start = lb(g), end = lb(g + 1);
    float sum = 0.f;
    for (int i = start + w; i < end; i += 4) {
        float v = bf2f(h2[(size_t)i * 64 + lane]);
        sum += v > 0.f ? v : 0.f;
    }
    __shared__ float ps[4][64];
    ps[w][lane] = sum;
    __syncthreads();
    if (w == 0) {
        float tot = ps[0][lane] + ps[1][lane] + ps[2][lane] + ps[3][lane];
        int cntn = end - start;
        ps[0][lane] = tot / (float)(cntn > 0 ? cntn : 1);
    }
    __syncthreads();
    if (threadIdx.x < 10) {
        float o = cls_b[threadIdx.x];
#pragma unroll
        for (int j = 0; j < 64; ++j) o = fmaf(ps[0][j], cls_w[j * 10 + threadIdx.x], o);
        out[g * 10 + threadIdx.x] = o;
    }
}

// ---------------------------------------------------------------------------
extern "C" void kernel_launch(void* const* d_in, const int* in_sizes, int n_in,
                              void* d_out, int out_size, void* d_ws, size_t ws_size,
                              hipStream_t stream) {
    const int*   node_x = (const int*)d_in[0];
    const int*   ei     = (const int*)d_in[1];
    const int*   et     = (const int*)d_in[2];
    const int*   batch  = (const int*)d_in[3];
    const float* pre_w  = (const float*)d_in[4];
    const float* pre_b  = (const float*)d_in[5];
    const float* w1     = (const float*)d_in[6];
    const float* root1  = (const float*)d_in[7];
    const float* b1     = (const float*)d_in[8];
    const float* w2     = (const float*)d_in[9];
    const float* root2  = (const float*)d_in[10];
    const float* b2     = (const float*)d_in[11];
    const float* cls_w  = (const float*)d_in[12];
    const float* cls_b  = (const float*)d_in[13];
    float* out = (float*)d_out;

    int N = in_sizes[0] / 2;
    int E = in_sizes[1] / 2;
    int G = out_size / 10;

    int NB = (N + BNODES - 1) >> BSH;
    int chunk = (E + NBLK_A - 1) / NBLK_A;
    int nh = NB * NBLK_A;
    int nscan = (nh + 1023) / 1024;
    int EP = E + NB * BNODES * 3;      // whole-node pads (<=3/node)

    char* ws = (char*)d_ws;
    size_t off_b = 0;
    auto alloc = [&](size_t bytes) {
        void* p = ws + off_b;
        off_b = (off_b + bytes + 255) & ~(size_t)255;
        return p;
    };
    unsigned short* B1f    = (unsigned short*)alloc(4 * 6 * 64 * 8 * sizeof(short));
    float*          root1t = (float*)alloc(64 * 64 * sizeof(float));
    unsigned short* B2f    = (unsigned short*)alloc(16 * 2 * 64 * 8 * sizeof(short));
    unsigned char*  combo  = (unsigned char*)alloc((size_t)N + 64);
    int*            hist   = (int*)alloc((size_t)nh * sizeof(int));
    int*            hoff   = (int*)alloc((size_t)nh * sizeof(int));
    int*            bsums  = (int*)alloc(128 * sizeof(int));
    unsigned*       staged = (unsigned*)alloc((size_t)E * sizeof(unsigned));
    unsigned*       edges1 = (unsigned*)alloc((size_t)EP * sizeof(unsigned));
    uint2*          edges2 = (uint2*)alloc(((size_t)EP + 16) * sizeof(uint2));
    int*            base1  = (int*)alloc(((size_t)N + 8) * sizeof(int));
    unsigned short* plen   = (unsigned short*)alloc(((size_t)N + 8) * sizeof(short));
    unsigned short* h1     = (unsigned short*)alloc((size_t)(N + 16) * 64 * sizeof(short));
    unsigned short* Rb     = (unsigned short*)alloc((size_t)N * 64 * sizeof(short));
    unsigned short* Y      = (unsigned short*)alloc((size_t)3 * N * 64 * sizeof(short));
    unsigned short* h2     = (unsigned short*)alloc((size_t)N * 64 * sizeof(short));

    setup_kernel<<<64, 256, 0, stream>>>(pre_w, pre_b, w1, root1, b1, root2, w2,
                                         B1f, root1t, B2f);
    combo_kernel<<<(N + 255) / 256, 256, 0, stream>>>(node_x, combo, N);

    hist_kernel<<<NBLK_A, 256, 0, stream>>>(ei, hist, E, NB, chunk);
    scan1<<<nscan, 1024, 0, stream>>>(hist, hoff, bsums, nh);
    scan2<<<1, 128, 0, stream>>>(bsums, nscan);
    scan3<<<nscan, 1024, 0, stream>>>(hoff, bsums, nh);
    place_kernel<<<NBLK_A, 256, 0, stream>>>(ei, et, hoff, staged, E, NB, chunk);
    finalize_kernel<<<NB, 256, 0, stream>>>(staged, hoff, combo, edges1, edges2,
                                            base1, plen, E, N, NB);

    conv1_mfma<<<(N + 63) / 64, 256, 0, stream>>>(edges1, base1, B1f, root1t, combo, h1, N);
    gemm_Y<<<((N + 15) / 16 + 3) / 4, 256, 0, stream>>>(h1, B2f, b2, Rb, Y, N);
    conv2_gather<<<(N + 7) / 8, 256, 0, stream>>>(edges2, base1, plen, (const uint4*)Y,
                                                  (const uint4*)Rb, (uint4*)h2, N);
    pool_cls<<<G, 256, 0, stream>>>(h2, batch, cls_w, cls_b, out, N, G);
}

// Round 16
// 169.430 us; speedup vs baseline: 6.6431x; 1.0291x over previous
//
#include <hip/hip_runtime.h>

#define BSH 9              // 512 nodes per dst bucket
#define BNODES 512
#define NBLK_A 256         // blocks in hist/place passes

typedef __attribute__((ext_vector_type(8))) short short8;
typedef __attribute__((ext_vector_type(4))) float floatx4;

static __device__ inline float bf2f(unsigned short u) {
    union { unsigned int i; float f; } v; v.i = ((unsigned int)u) << 16; return v.f;
}
static __device__ inline unsigned f2bf(float f) {
    union { float f; unsigned int i; } v; v.f = f;
    unsigned int x = v.i;
    return (x + 0x7FFF + ((x >> 16) & 1)) >> 16;  // RNE
}
static __device__ inline float asf(unsigned int u) {
    union { unsigned int i; float f; } v; v.i = u; return v.f;
}
static __device__ inline unsigned asu(float f) {
    union { float f; unsigned int i; } v; v.f = f; return v.i;
}

// ---------------------------------------------------------------------------
// K1 (merged setup): per-combo tables + B2 fragments.
// ---------------------------------------------------------------------------
__global__ void __launch_bounds__(256) setup_kernel(
        const float* __restrict__ pre_w, const float* __restrict__ pre_b,
        const float* __restrict__ w1, const float* __restrict__ root1,
        const float* __restrict__ b1, const float* __restrict__ root2,
        const float* __restrict__ w2,
        unsigned short* __restrict__ B1f, float* __restrict__ root1t,
        unsigned short* __restrict__ B2f) {
    int combo = blockIdx.x;
    int t = threadIdx.x;
    __shared__ float x1s[32];
    if (t < 32) {
        int s = combo >> 3, c = combo & 7;
        float v = pre_w[s * 32 + t] + pre_w[(8 + c) * 32 + t] + pre_b[t];
        x1s[t] = v > 0.f ? v : 0.f;
    }
    __syncthreads();
    if (t < 64) {
        int j = t;
        float acc = b1[j];
#pragma unroll
        for (int k = 0; k < 32; ++k) acc = fmaf(x1s[k], root1[k * 64 + j], acc);
        root1t[combo * 64 + j] = acc;
        for (int r = 0; r < 3; ++r) {
            float a = 0.f;
#pragma unroll
            for (int k = 0; k < 32; ++k) a = fmaf(x1s[k], w1[(r * 32 + k) * 64 + j], a);
            int idx = (r << 6) | combo;            // B row
            int kt = idx >> 5, i = idx & 7, lrow = (idx >> 3) & 3;
            int nt = j >> 4;
            int l = (lrow << 4) | (j & 15);
            B1f[(((nt * 6 + kt) * 64) + l) * 8 + i] = (unsigned short)f2bf(a);
        }
    }
    {   // B2f: [root2 | W2_0 | W2_1 | W2_2] fragments
        int tt = combo * 256 + t;                  // 0 .. 16383
        int i = tt & 7, l = (tt >> 3) & 63, kt = (tt >> 9) & 1, nt = tt >> 10;
        int k = kt * 32 + ((l >> 4) * 8) + i;
        int col = nt * 16 + (l & 15);
        float v;
        if (col < 64) v = root2[k * 64 + col];
        else {
            int r = (col - 64) >> 6, wcol = (col - 64) & 63;
            v = w2[(r * 64 + k) * 64 + wcol];
        }
        B2f[tt] = (unsigned short)f2bf(v);
    }
}

// K3: combo[i] as u8
__global__ void combo_kernel(const int* __restrict__ node_x, unsigned char* __restrict__ combo, int N) {
    int i = blockIdx.x * blockDim.x + threadIdx.x;
    if (i < N) combo[i] = (unsigned char)(node_x[2 * i] * 8 + node_x[2 * i + 1]);
}

// ---------------------------------------------------------------------------
// K4 (pass A0): per-block dst-bucket histogram. hist[b*NBLK_A + blk]
// ---------------------------------------------------------------------------
__global__ void __launch_bounds__(256) hist_kernel(const int* __restrict__ ei,
                                                   int* __restrict__ hist, int E, int NB, int chunk) {
    __shared__ int lh[256];
    for (int t = threadIdx.x; t < NB; t += 256) lh[t] = 0;
    __syncthreads();
    int s = blockIdx.x * chunk, e1 = min(E, s + chunk);
    for (int e = s + threadIdx.x; e < e1; e += 256)
        atomicAdd(&lh[ei[E + e] >> BSH], 1);
    __syncthreads();
    for (int b = threadIdx.x; b < NB; b += 256) hist[b * NBLK_A + blockIdx.x] = lh[b];
}

// generic exclusive scan (3 kernels)
__global__ void scan1(const int* __restrict__ in, int* __restrict__ out,
                      int* __restrict__ bsums, int n) {
    __shared__ int s[1024];
    int i = blockIdx.x * 1024 + threadIdx.x;
    int d = (i < n) ? in[i] : 0;
    s[threadIdx.x] = d;
    __syncthreads();
    for (int off = 1; off < 1024; off <<= 1) {
        int v = (threadIdx.x >= off) ? s[threadIdx.x - off] : 0;
        __syncthreads();
        s[threadIdx.x] += v;
        __syncthreads();
    }
    if (i < n) out[i] = s[threadIdx.x] - d;
    if (threadIdx.x == 1023) bsums[blockIdx.x] = s[1023];
}
__global__ void scan2(int* __restrict__ bsums, int nb) {
    __shared__ int s[128];
    int v = (threadIdx.x < nb) ? bsums[threadIdx.x] : 0;
    s[threadIdx.x] = v;
    __syncthreads();
    for (int off = 1; off < 128; off <<= 1) {
        int u = (threadIdx.x >= off) ? s[threadIdx.x - off] : 0;
        __syncthreads();
        s[threadIdx.x] += u;
        __syncthreads();
    }
    if (threadIdx.x < nb) bsums[threadIdx.x] = s[threadIdx.x] - v;
}
__global__ void scan3(int* __restrict__ out, const int* __restrict__ bsums, int n) {
    int i = blockIdx.x * 1024 + threadIdx.x;
    if (i < n) out[i] += bsums[blockIdx.x];
}

// ---------------------------------------------------------------------------
// K5 (pass A1): place edges into dst-buckets. staged = dloc<<19 | rel<<17 | src
// ---------------------------------------------------------------------------
__global__ void __launch_bounds__(256) place_kernel(const int* __restrict__ ei, const int* __restrict__ et,
                                                    const int* __restrict__ off, unsigned* __restrict__ staged,
                                                    int E, int NB, int chunk) {
    __shared__ int lh[256];
    for (int t = threadIdx.x; t < NB; t += 256) lh[t] = 0;
    __syncthreads();
    int s = blockIdx.x * chunk, e1 = min(E, s + chunk);
    for (int e = s + threadIdx.x; e < e1; e += 256) {
        int d = ei[E + e];
        int b = d >> BSH;
        int lr = atomicAdd(&lh[b], 1);
        int pos = off[b * NBLK_A + blockIdx.x] + lr;
        staged[pos] = ((unsigned)(d & (BNODES - 1)) << 19) | ((unsigned)et[e] << 17) | (unsigned)ei[e];
    }
}

// ---------------------------------------------------------------------------
// K6 (pass B): finalize into whole-node x4-padded CSR with per-edge
// precomputed weight w = 1/cnt(dst,rel).
// ---------------------------------------------------------------------------
__global__ void __launch_bounds__(256) finalize_kernel(
        const unsigned* __restrict__ staged, const int* __restrict__ off,
        const unsigned char* __restrict__ combo,
        unsigned* __restrict__ edges1, uint2* __restrict__ edges2,
        int* __restrict__ base1, unsigned short* __restrict__ plen,
        int E, int N, int NB) {
    __shared__ int lrel[BNODES * 3];   // per-(node,rel) counts (stay counts)
    __shared__ float lwf[BNODES * 3];  // 1/count
    __shared__ int lcnt[BNODES];       // placement cursors
    __shared__ int part[256];
    int blk = blockIdx.x;
    int d0 = blk * BNODES;
    int nn = min(BNODES, N - d0);
    int estart = off[blk * NBLK_A];
    int eend = (blk == NB - 1) ? E : off[(blk + 1) * NBLK_A];
    int ebase = estart + blk * (BNODES * 3);   // padded-capacity base
    for (int t = threadIdx.x; t < BNODES * 3; t += 256) lrel[t] = 0;
    __syncthreads();
    for (int e = estart + threadIdx.x; e < eend; e += 256) {
        unsigned p = staged[e];
        atomicAdd(&lrel[(p >> 19) * 3 + ((p >> 17) & 3)], 1);
    }
    __syncthreads();
    for (int j = threadIdx.x; j < BNODES * 3; j += 256) {
        int c = lrel[j];
        lwf[j] = c ? 1.f / (float)c : 0.f;
    }
    // padded exclusive scan over whole-node lengths (2 nodes/thread)
    int t = threadIdx.x;
    int n0 = 2 * t, n1 = 2 * t + 1;
    int ct0 = lrel[n0 * 3] + lrel[n0 * 3 + 1] + lrel[n0 * 3 + 2];
    int ct1 = lrel[n1 * 3] + lrel[n1 * 3 + 1] + lrel[n1 * 3 + 2];
    int pl0 = (ct0 + 3) & ~3, pl1 = (ct1 + 3) & ~3;
    int sum = pl0 + pl1;
    part[t] = sum;
    __syncthreads();
    for (int o = 1; o < 256; o <<= 1) {
        int u = (t >= o) ? part[t - o] : 0;
        __syncthreads();
        part[t] += u;
        __syncthreads();
    }
    int run = ebase + part[t] - sum;
    lcnt[n0] = run;
    lcnt[n1] = run + pl0;
    if (n0 < nn) { base1[d0 + n0] = run;       plen[d0 + n0] = (unsigned short)pl0; }
    if (n1 < nn) { base1[d0 + n1] = run + pl0; plen[d0 + n1] = (unsigned short)pl1; }
    if (blk == NB - 1 && t == 255) base1[N] = ebase + part[255];   // sentinel
    __syncthreads();
    for (int e = estart + threadIdx.x; e < eend; e += 256) {
        unsigned p = staged[e];
        int dloc = p >> 19;
        unsigned rel = (p >> 17) & 3;
        unsigned src = p & 0x1FFFF;
        float w = lwf[dloc * 3 + rel];
        int slot = atomicAdd(&lcnt[dloc], 1);
        uint2 e2;
        e2.x = (rel * (unsigned)N + src) * 16u;
        e2.y = asu(w);
        edges2[slot] = e2;
        edges1[slot] = (f2bf(w) << 16) | ((unsigned)(dloc & 63) << 8)
                     | (rel << 6) | (unsigned)combo[src];
    }
    __syncthreads();
    for (int n = threadIdx.x; n < nn; n += 256) {
        int ct = lrel[n * 3] + lrel[n * 3 + 1] + lrel[n * 3 + 2];
        int need = ((ct + 3) & ~3) - ct;          // 0..3 pads, w = 0
        int cur = lcnt[n];
        for (int k = 0; k < need; ++k) {
            uint2 z; z.x = 0u; z.y = 0u;
            edges2[cur + k] = z;
            edges1[cur + k] = 0u;        // w=0 -> contributes nothing
        }
    }
}

// ---------------------------------------------------------------------------
// K7: conv1 as count-matrix MFMA. Block = 64 nodes, 512 THREADS (8 waves)
// for occupancy: 50 KB LDS caps 3 blocks/CU; 8 waves/block -> 24 waves/CU.
// MFMA phase: 2 waves per 16-node tile, each wave does 2 of 4 nt tiles.
// ---------------------------------------------------------------------------
#define CSTR 196
__global__ void __launch_bounds__(512) conv1_mfma(
        const unsigned* __restrict__ edges1, const int* __restrict__ base1,
        const unsigned short* __restrict__ B1f, const float* __restrict__ root1t,
        const unsigned char* __restrict__ combo, unsigned short* __restrict__ h1, int N) {
    __shared__ float Cs[64 * CSTR];
    for (int t = threadIdx.x; t < 64 * CSTR; t += 512) Cs[t] = 0.f;
    __syncthreads();
    int g0 = blockIdx.x * 64;
    int gEnd = min(g0 + 64, N);
    int estart = base1[g0], eend = base1[gEnd];
    for (int e = estart + threadIdx.x; e < eend; e += 512) {
        unsigned ew = edges1[e];
        float wt = asf(ew & 0xFFFF0000u);        // bf16 weight in high bits
        int nl = (ew >> 8) & 63;
        int idx = ew & 255u;
        atomicAdd(&Cs[nl * CSTR + idx], wt);
    }
    __syncthreads();
    int lane = threadIdx.x & 63;
    int w0 = threadIdx.x >> 6;          // 0..7
    int tile = w0 >> 1;                 // 16-node tile 0..3
    int node0 = g0 + 16 * tile;
    if (node0 >= N) return;
    int m = lane & 15, kg = lane >> 4;
    const float* cr = &Cs[(16 * tile + m) * CSTR];
    short8 a[6];
#pragma unroll
    for (int kt = 0; kt < 6; ++kt) {
        float4 ca = *(const float4*)(cr + kt * 32 + kg * 8);
        float4 cb = *(const float4*)(cr + kt * 32 + kg * 8 + 4);
        short8 av;
        av[0] = (short)f2bf(ca.x); av[1] = (short)f2bf(ca.y);
        av[2] = (short)f2bf(ca.z); av[3] = (short)f2bf(ca.w);
        av[4] = (short)f2bf(cb.x); av[5] = (short)f2bf(cb.y);
        av[6] = (short)f2bf(cb.z); av[7] = (short)f2bf(cb.w);
        a[kt] = av;
    }
#pragma unroll
    for (int nt2 = 0; nt2 < 2; ++nt2) {
        int nt = (w0 & 1) * 2 + nt2;
        floatx4 c = {0.f, 0.f, 0.f, 0.f};
#pragma unroll
        for (int kt = 0; kt < 6; ++kt) {
            short8 b = *(const short8*)(B1f + ((nt * 6 + kt) * 64 + lane) * 8);
            c = __builtin_amdgcn_mfma_f32_16x16x32_bf16(a[kt], b, c, 0, 0, 0);
        }
#pragma unroll
        for (int q = 0; q < 4; ++q) {
            int node = node0 + kg * 4 + q;
            if (node < N) {
                float v = c[q] + root1t[(int)combo[node] * 64 + nt * 16 + m];
                v = v > 0.f ? v : 0.f;
                h1[(size_t)node * 64 + nt * 16 + m] = (unsigned short)f2bf(v);
            }
        }
    }
}

// ---------------------------------------------------------------------------
// K8: gemm_Y. [16,64]@[64,256] MFMA per wave: cols 0..63 -> R = h1@root2+b2,
// cols 64..255 -> Y_r = h1@W2_r. All bf16 out.
// ---------------------------------------------------------------------------
__global__ void __launch_bounds__(256) gemm_Y(
        const unsigned short* __restrict__ h1, const unsigned short* __restrict__ B2f,
        const float* __restrict__ b2, unsigned short* __restrict__ Rb,
        unsigned short* __restrict__ Y, int N) {
    int g = blockIdx.x * 4 + (threadIdx.x >> 6);
    int node0 = g * 16;
    if (node0 >= N) return;
    int lane = threadIdx.x & 63;
    int m = lane & 15, kg = lane >> 4;
    short8 a[2];
#pragma unroll
    for (int kt = 0; kt < 2; ++kt)
        a[kt] = *(const short8*)(h1 + (size_t)(node0 + m) * 64 + kt * 32 + kg * 8);
#pragma unroll
    for (int nt = 0; nt < 16; ++nt) {
        floatx4 c = {0.f, 0.f, 0.f, 0.f};
#pragma unroll
        for (int kt = 0; kt < 2; ++kt) {
            short8 b = *(const short8*)(B2f + ((nt * 2 + kt) * 64 + lane) * 8);
            c = __builtin_amdgcn_mfma_f32_16x16x32_bf16(a[kt], b, c, 0, 0, 0);
        }
        if (nt < 4) {
            int col = nt * 16 + m;
            float bias = b2[col];
#pragma unroll
            for (int q = 0; q < 4; ++q) {
                int node = node0 + kg * 4 + q;
                if (node < N) Rb[(size_t)node * 64 + col] = (unsigned short)f2bf(c[q] + bias);
            }
        } else {
            int r = (nt - 4) >> 2;
            int ycol = ((nt - 4) & 3) * 16 + m;
#pragma unroll
            for (int q = 0; q < 4; ++q) {
                int node = node0 + kg * 4 + q;
                if (node < N)
                    Y[((size_t)r * N + node) * 64 + ycol] = (unsigned short)f2bf(c[q]);
            }
        }
    }
}

// ---------------------------------------------------------------------------
// K9: conv2 gather, HALF-WAVE per node. 8 lanes x uint4 (16B) per edge ->
// 4 edges/iter per node; unroll x2. h2 = R + sum (pre-relu).
// ---------------------------------------------------------------------------
__global__ void __launch_bounds__(256) conv2_gather(
        const uint2* __restrict__ edges2, const int* __restrict__ base1,
        const unsigned short* __restrict__ plen, const uint4* __restrict__ Yu4,
        const uint4* __restrict__ Ru4, uint4* __restrict__ h2u4, int N) {
    int i = blockIdx.x * 8 + (threadIdx.x >> 5);   // node per 32-lane half
    if (i >= N) return;
    int l5 = threadIdx.x & 31;
    int el = l5 >> 3;        // edge slot 0..3
    int dl = l5 & 7;         // dim octet 0..7 (8 bf16 each)
    int s = base1[i];
    int L = plen[i];
    float f0 = 0.f, f1 = 0.f, f2 = 0.f, f3 = 0.f;
    float f4 = 0.f, f5 = 0.f, f6 = 0.f, f7 = 0.f;
    int t2 = 0;
    for (; t2 + 8 <= L; t2 += 8) {
        uint2 ea = edges2[s + t2 + el];
        uint2 eb = edges2[s + t2 + 4 + el];
        uint4 va = Yu4[(size_t)(ea.x >> 1) + dl];
        uint4 vb = Yu4[(size_t)(eb.x >> 1) + dl];
        float wa = asf(ea.y), wb = asf(eb.y);
        f0 = fmaf(wa, asf(va.x << 16), f0);
        f1 = fmaf(wa, asf(va.x & 0xFFFF0000u), f1);
        f2 = fmaf(wa, asf(va.y << 16), f2);
        f3 = fmaf(wa, asf(va.y & 0xFFFF0000u), f3);
        f4 = fmaf(wa, asf(va.z << 16), f4);
        f5 = fmaf(wa, asf(va.z & 0xFFFF0000u), f5);
        f6 = fmaf(wa, asf(va.w << 16), f6);
        f7 = fmaf(wa, asf(va.w & 0xFFFF0000u), f7);
        f0 = fmaf(wb, asf(vb.x << 16), f0);
        f1 = fmaf(wb, asf(vb.x & 0xFFFF0000u), f1);
        f2 = fmaf(wb, asf(vb.y << 16), f2);
        f3 = fmaf(wb, asf(vb.y & 0xFFFF0000u), f3);
        f4 = fmaf(wb, asf(vb.z << 16), f4);
        f5 = fmaf(wb, asf(vb.z & 0xFFFF0000u), f5);
        f6 = fmaf(wb, asf(vb.w << 16), f6);
        f7 = fmaf(wb, asf(vb.w & 0xFFFF0000u), f7);
    }
    if (t2 < L) {
        uint2 ea = edges2[s + t2 + el];
        uint4 va = Yu4[(size_t)(ea.x >> 1) + dl];
        float wa = asf(ea.y);
        f0 = fmaf(wa, asf(va.x << 16), f0);
        f1 = fmaf(wa, asf(va.x & 0xFFFF0000u), f1);
        f2 = fmaf(wa, asf(va.y << 16), f2);
        f3 = fmaf(wa, asf(va.y & 0xFFFF0000u), f3);
        f4 = fmaf(wa, asf(va.z << 16), f4);
        f5 = fmaf(wa, asf(va.z & 0xFFFF0000u), f5);
        f6 = fmaf(wa, asf(va.w << 16), f6);
        f7 = fmaf(wa, asf(va.w & 0xFFFF0000u), f7);
    }
    f0 += __shfl_xor(f0, 8); f0 += __shfl_xor(f0, 16);
    f1 += __shfl_xor(f1, 8); f1 += __shfl_xor(f1, 16);
    f2 += __shfl_xor(f2, 8); f2 += __shfl_xor(f2, 16);
    f3 += __shfl_xor(f3, 8); f3 += __shfl_xor(f3, 16);
    f4 += __shfl_xor(f4, 8); f4 += __shfl_xor(f4, 16);
    f5 += __shfl_xor(f5, 8); f5 += __shfl_xor(f5, 16);
    f6 += __shfl_xor(f6, 8); f6 += __shfl_xor(f6, 16);
    f7 += __shfl_xor(f7, 8); f7 += __shfl_xor(f7, 16);
    if (el == 0) {
        uint4 rb = Ru4[(size_t)i * 8 + dl];
        f0 += asf(rb.x << 16);
        f1 += asf(rb.x & 0xFFFF0000u);
        f2 += asf(rb.y << 16);
        f3 += asf(rb.y & 0xFFFF0000u);
        f4 += asf(rb.z << 16);
        f5 += asf(rb.z & 0xFFFF0000u);
        f6 += asf(rb.w << 16);
        f7 += asf(rb.w & 0xFFFF0000u);
        uint4 o;
        o.x = f2bf(f0) | (f2bf(f1) << 16);
        o.y = f2bf(f2) | (f2bf(f3) << 16);
        o.z = f2bf(f4) | (f2bf(f5) << 16);
        o.w = f2bf(f6) | (f2bf(f7) << 16);
        h2u4[(size_t)i * 8 + dl] = o;
    }
}

// ---------------------------------------------------------------------------
// K10: mean-pool + classifier, 4 waves per graph.
// ---------------------------------------------------------------------------
__global__ void __launch_bounds__(256) pool_cls(
        const unsigned short* __restrict__ h2, const int* __restrict__ batch,
        const float* __restrict__ cls_w, const float* __restrict__ cls_b,
        float* __restrict__ out, int N, int G) {
    int g = blockIdx.x;
    int lane = threadIdx.x & 63, w = threadIdx.x >> 6;
    auto lb = [&](int key) {
        int lo = 0, hi = N;
        while (lo < hi) { int mid = (lo + hi) >> 1; if (batch[mid] < key) lo = mid + 1; else hi = mid; }
        return lo;
    };
    int start = lb(g), end = lb(g + 1);
    float sum = 0.f;
    for (int i = start + w; i < end; i += 4) {
        float v = bf2f(h2[(size_t)i * 64 + lane]);
        sum += v > 0.f ? v : 0.f;
    }
    __shared__ float ps[4][64];
    ps[w][lane] = sum;
    __syncthreads();
    if (w == 0) {
        float tot = ps[0][lane] + ps[1][lane] + ps[2][lane] + ps[3][lane];
        int cntn = end - start;
        ps[0][lane] = tot / (float)(cntn > 0 ? cntn : 1);
    }
    __syncthreads();
    if (threadIdx.x < 10) {
        float o = cls_b[threadIdx.x];
#pragma unroll
        for (int j = 0; j < 64; ++j) o = fmaf(ps[0][j], cls_w[j * 10 + threadIdx.x], o);
        out[g * 10 + threadIdx.x] = o;
    }
}

// ---------------------------------------------------------------------------
extern "C" void kernel_launch(void* const* d_in, const int* in_sizes, int n_in,
                              void* d_out, int out_size, void* d_ws, size_t ws_size,
                              hipStream_t stream) {
    const int*   node_x = (const int*)d_in[0];
    const int*   ei     = (const int*)d_in[1];
    const int*   et     = (const int*)d_in[2];
    const int*   batch  = (const int*)d_in[3];
    const float* pre_w  = (const float*)d_in[4];
    const float* pre_b  = (const float*)d_in[5];
    const float* w1     = (const float*)d_in[6];
    const float* root1  = (const float*)d_in[7];
    const float* b1     = (const float*)d_in[8];
    const float* w2     = (const float*)d_in[9];
    const float* root2  = (const float*)d_in[10];
    const float* b2     = (const float*)d_in[11];
    const float* cls_w  = (const float*)d_in[12];
    const float* cls_b  = (const float*)d_in[13];
    float* out = (float*)d_out;

    int N = in_sizes[0] / 2;
    int E = in_sizes[1] / 2;
    int G = out_size / 10;

    int NB = (N + BNODES - 1) >> BSH;
    int chunk = (E + NBLK_A - 1) / NBLK_A;
    int nh = NB * NBLK_A;
    int nscan = (nh + 1023) / 1024;
    int EP = E + NB * BNODES * 3;      // whole-node pads (<=3/node)

    char* ws = (char*)d_ws;
    size_t off_b = 0;
    auto alloc = [&](size_t bytes) {
        void* p = ws + off_b;
        off_b = (off_b + bytes + 255) & ~(size_t)255;
        return p;
    };
    unsigned short* B1f    = (unsigned short*)alloc(4 * 6 * 64 * 8 * sizeof(short));
    float*          root1t = (float*)alloc(64 * 64 * sizeof(float));
    unsigned short* B2f    = (unsigned short*)alloc(16 * 2 * 64 * 8 * sizeof(short));
    unsigned char*  combo  = (unsigned char*)alloc((size_t)N + 64);
    int*            hist   = (int*)alloc((size_t)nh * sizeof(int));
    int*            hoff   = (int*)alloc((size_t)nh * sizeof(int));
    int*            bsums  = (int*)alloc(128 * sizeof(int));
    unsigned*       staged = (unsigned*)alloc((size_t)E * sizeof(unsigned));
    unsigned*       edges1 = (unsigned*)alloc((size_t)EP * sizeof(unsigned));
    uint2*          edges2 = (uint2*)alloc(((size_t)EP + 16) * sizeof(uint2));
    int*            base1  = (int*)alloc(((size_t)N + 8) * sizeof(int));
    unsigned short* plen   = (unsigned short*)alloc(((size_t)N + 8) * sizeof(short));
    unsigned short* h1     = (unsigned short*)alloc((size_t)(N + 16) * 64 * sizeof(short));
    unsigned short* Rb     = (unsigned short*)alloc((size_t)N * 64 * sizeof(short));
    unsigned short* Y      = (unsigned short*)alloc((size_t)3 * N * 64 * sizeof(short));
    unsigned short* h2     = (unsigned short*)alloc((size_t)N * 64 * sizeof(short));

    setup_kernel<<<64, 256, 0, stream>>>(pre_w, pre_b, w1, root1, b1, root2, w2,
                                         B1f, root1t, B2f);
    combo_kernel<<<(N + 255) / 256, 256, 0, stream>>>(node_x, combo, N);

    hist_kernel<<<NBLK_A, 256, 0, stream>>>(ei, hist, E, NB, chunk);
    scan1<<<nscan, 1024, 0, stream>>>(hist, hoff, bsums, nh);
    scan2<<<1, 128, 0, stream>>>(bsums, nscan);
    scan3<<<nscan, 1024, 0, stream>>>(hoff, bsums, nh);
    place_kernel<<<NBLK_A, 256, 0, stream>>>(ei, et, hoff, staged, E, NB, chunk);
    finalize_kernel<<<NB, 256, 0, stream>>>(staged, hoff, combo, edges1, edges2,
                                            base1, plen, E, N, NB);

    conv1_mfma<<<(N + 63) / 64, 512, 0, stream>>>(edges1, base1, B1f, root1t, combo, h1, N);
    gemm_Y<<<((N + 15) / 16 + 3) / 4, 256, 0, stream>>>(h1, B2f, b2, Rb, Y, N);
    conv2_gather<<<(N + 7) / 8, 256, 0, stream>>>(edges2, base1, plen, (const uint4*)Y,
                                                  (const uint4*)Rb, (uint4*)h2, N);
    pool_cls<<<G, 256, 0, stream>>>(h2, batch, cls_w, cls_b, out, N, G);
}

// Round 17
// 159.693 us; speedup vs baseline: 7.0482x; 1.0610x over previous
//
#include <hip/hip_runtime.h>

#define BSH 9              // 512 nodes per dst bucket
#define BNODES 512
#define NBLK_A 256         // blocks in hist/place passes

typedef __attribute__((ext_vector_type(8))) short short8;
typedef __attribute__((ext_vector_type(4))) float floatx4;

static __device__ inline float bf2f(unsigned short u) {
    union { unsigned int i; float f; } v; v.i = ((unsigned int)u) << 16; return v.f;
}
static __device__ inline unsigned f2bf(float f) {
    union { float f; unsigned int i; } v; v.f = f;
    unsigned int x = v.i;
    return (x + 0x7FFF + ((x >> 16) & 1)) >> 16;  // RNE
}
static __device__ inline float asf(unsigned int u) {
    union { unsigned int i; float f; } v; v.i = u; return v.f;
}
static __device__ inline unsigned asu(float f) {
    union { float f; unsigned int i; } v; v.f = f; return v.i;
}

// ---------------------------------------------------------------------------
// K1 (merged setup): per-combo tables + B2 fragments.
// ---------------------------------------------------------------------------
__global__ void __launch_bounds__(256) setup_kernel(
        const float* __restrict__ pre_w, const float* __restrict__ pre_b,
        const float* __restrict__ w1, const float* __restrict__ root1,
        const float* __restrict__ b1, const float* __restrict__ root2,
        const float* __restrict__ w2,
        unsigned short* __restrict__ B1f, float* __restrict__ root1t,
        unsigned short* __restrict__ B2f) {
    int combo = blockIdx.x;
    int t = threadIdx.x;
    __shared__ float x1s[32];
    if (t < 32) {
        int s = combo >> 3, c = combo & 7;
        float v = pre_w[s * 32 + t] + pre_w[(8 + c) * 32 + t] + pre_b[t];
        x1s[t] = v > 0.f ? v : 0.f;
    }
    __syncthreads();
    if (t < 64) {
        int j = t;
        float acc = b1[j];
#pragma unroll
        for (int k = 0; k < 32; ++k) acc = fmaf(x1s[k], root1[k * 64 + j], acc);
        root1t[combo * 64 + j] = acc;
        for (int r = 0; r < 3; ++r) {
            float a = 0.f;
#pragma unroll
            for (int k = 0; k < 32; ++k) a = fmaf(x1s[k], w1[(r * 32 + k) * 64 + j], a);
            int idx = (r << 6) | combo;            // B row
            int kt = idx >> 5, i = idx & 7, lrow = (idx >> 3) & 3;
            int nt = j >> 4;
            int l = (lrow << 4) | (j & 15);
            B1f[(((nt * 6 + kt) * 64) + l) * 8 + i] = (unsigned short)f2bf(a);
        }
    }
    {   // B2f: [root2 | W2_0 | W2_1 | W2_2] fragments
        int tt = combo * 256 + t;                  // 0 .. 16383
        int i = tt & 7, l = (tt >> 3) & 63, kt = (tt >> 9) & 1, nt = tt >> 10;
        int k = kt * 32 + ((l >> 4) * 8) + i;
        int col = nt * 16 + (l & 15);
        float v;
        if (col < 64) v = root2[k * 64 + col];
        else {
            int r = (col - 64) >> 6, wcol = (col - 64) & 63;
            v = w2[(r * 64 + k) * 64 + wcol];
        }
        B2f[tt] = (unsigned short)f2bf(v);
    }
}

// K3: combo[i] as u8
__global__ void combo_kernel(const int* __restrict__ node_x, unsigned char* __restrict__ combo, int N) {
    int i = blockIdx.x * blockDim.x + threadIdx.x;
    if (i < N) combo[i] = (unsigned char)(node_x[2 * i] * 8 + node_x[2 * i + 1]);
}

// ---------------------------------------------------------------------------
// K4 (pass A0): per-block dst-bucket histogram. hist[b*NBLK_A + blk]
// ---------------------------------------------------------------------------
__global__ void __launch_bounds__(256) hist_kernel(const int* __restrict__ ei,
                                                   int* __restrict__ hist, int E, int NB, int chunk) {
    __shared__ int lh[256];
    for (int t = threadIdx.x; t < NB; t += 256) lh[t] = 0;
    __syncthreads();
    int s = blockIdx.x * chunk, e1 = min(E, s + chunk);
    for (int e = s + threadIdx.x; e < e1; e += 256)
        atomicAdd(&lh[ei[E + e] >> BSH], 1);
    __syncthreads();
    for (int b = threadIdx.x; b < NB; b += 256) hist[b * NBLK_A + blockIdx.x] = lh[b];
}

// generic exclusive scan (3 kernels)
__global__ void scan1(const int* __restrict__ in, int* __restrict__ out,
                      int* __restrict__ bsums, int n) {
    __shared__ int s[1024];
    int i = blockIdx.x * 1024 + threadIdx.x;
    int d = (i < n) ? in[i] : 0;
    s[threadIdx.x] = d;
    __syncthreads();
    for (int off = 1; off < 1024; off <<= 1) {
        int v = (threadIdx.x >= off) ? s[threadIdx.x - off] : 0;
        __syncthreads();
        s[threadIdx.x] += v;
        __syncthreads();
    }
    if (i < n) out[i] = s[threadIdx.x] - d;
    if (threadIdx.x == 1023) bsums[blockIdx.x] = s[1023];
}
__global__ void scan2(int* __restrict__ bsums, int nb) {
    __shared__ int s[128];
    int v = (threadIdx.x < nb) ? bsums[threadIdx.x] : 0;
    s[threadIdx.x] = v;
    __syncthreads();
    for (int off = 1; off < 128; off <<= 1) {
        int u = (threadIdx.x >= off) ? s[threadIdx.x - off] : 0;
        __syncthreads();
        s[threadIdx.x] += u;
        __syncthreads();
    }
    if (threadIdx.x < nb) bsums[threadIdx.x] = s[threadIdx.x] - v;
}
__global__ void scan3(int* __restrict__ out, const int* __restrict__ bsums, int n) {
    int i = blockIdx.x * 1024 + threadIdx.x;
    if (i < n) out[i] += bsums[blockIdx.x];
}

// ---------------------------------------------------------------------------
// K5 (pass A1): place edges into dst-buckets. staged = dloc<<19 | rel<<17 | src
// ---------------------------------------------------------------------------
__global__ void __launch_bounds__(256) place_kernel(const int* __restrict__ ei, const int* __restrict__ et,
                                                    const int* __restrict__ off, unsigned* __restrict__ staged,
                                                    int E, int NB, int chunk) {
    __shared__ int lh[256];
    for (int t = threadIdx.x; t < NB; t += 256) lh[t] = 0;
    __syncthreads();
    int s = blockIdx.x * chunk, e1 = min(E, s + chunk);
    for (int e = s + threadIdx.x; e < e1; e += 256) {
        int d = ei[E + e];
        int b = d >> BSH;
        int lr = atomicAdd(&lh[b], 1);
        int pos = off[b * NBLK_A + blockIdx.x] + lr;
        staged[pos] = ((unsigned)(d & (BNODES - 1)) << 19) | ((unsigned)et[e] << 17) | (unsigned)ei[e];
    }
}

// ---------------------------------------------------------------------------
// K6 (pass B): finalize into whole-node x4-padded CSR with per-edge
// precomputed weight w = 1/cnt(dst,rel).
// ---------------------------------------------------------------------------
__global__ void __launch_bounds__(256) finalize_kernel(
        const unsigned* __restrict__ staged, const int* __restrict__ off,
        const unsigned char* __restrict__ combo,
        unsigned* __restrict__ edges1, uint2* __restrict__ edges2,
        int* __restrict__ base1, unsigned short* __restrict__ plen,
        int E, int N, int NB) {
    __shared__ int lrel[BNODES * 3];   // per-(node,rel) counts (stay counts)
    __shared__ float lwf[BNODES * 3];  // 1/count
    __shared__ int lcnt[BNODES];       // placement cursors
    __shared__ int part[256];
    int blk = blockIdx.x;
    int d0 = blk * BNODES;
    int nn = min(BNODES, N - d0);
    int estart = off[blk * NBLK_A];
    int eend = (blk == NB - 1) ? E : off[(blk + 1) * NBLK_A];
    int ebase = estart + blk * (BNODES * 3);   // padded-capacity base
    for (int t = threadIdx.x; t < BNODES * 3; t += 256) lrel[t] = 0;
    __syncthreads();
    for (int e = estart + threadIdx.x; e < eend; e += 256) {
        unsigned p = staged[e];
        atomicAdd(&lrel[(p >> 19) * 3 + ((p >> 17) & 3)], 1);
    }
    __syncthreads();
    for (int j = threadIdx.x; j < BNODES * 3; j += 256) {
        int c = lrel[j];
        lwf[j] = c ? 1.f / (float)c : 0.f;
    }
    // padded exclusive scan over whole-node lengths (2 nodes/thread)
    int t = threadIdx.x;
    int n0 = 2 * t, n1 = 2 * t + 1;
    int ct0 = lrel[n0 * 3] + lrel[n0 * 3 + 1] + lrel[n0 * 3 + 2];
    int ct1 = lrel[n1 * 3] + lrel[n1 * 3 + 1] + lrel[n1 * 3 + 2];
    int pl0 = (ct0 + 3) & ~3, pl1 = (ct1 + 3) & ~3;
    int sum = pl0 + pl1;
    part[t] = sum;
    __syncthreads();
    for (int o = 1; o < 256; o <<= 1) {
        int u = (t >= o) ? part[t - o] : 0;
        __syncthreads();
        part[t] += u;
        __syncthreads();
    }
    int run = ebase + part[t] - sum;
    lcnt[n0] = run;
    lcnt[n1] = run + pl0;
    if (n0 < nn) { base1[d0 + n0] = run;       plen[d0 + n0] = (unsigned short)pl0; }
    if (n1 < nn) { base1[d0 + n1] = run + pl0; plen[d0 + n1] = (unsigned short)pl1; }
    if (blk == NB - 1 && t == 255) base1[N] = ebase + part[255];   // sentinel
    __syncthreads();
    for (int e = estart + threadIdx.x; e < eend; e += 256) {
        unsigned p = staged[e];
        int dloc = p >> 19;
        unsigned rel = (p >> 17) & 3;
        unsigned src = p & 0x1FFFF;
        float w = lwf[dloc * 3 + rel];
        int slot = atomicAdd(&lcnt[dloc], 1);
        uint2 e2;
        e2.x = (rel * (unsigned)N + src) * 16u;
        e2.y = asu(w);
        edges2[slot] = e2;
        edges1[slot] = (f2bf(w) << 16) | ((unsigned)(dloc & 63) << 8)
                     | (rel << 6) | (unsigned)combo[src];
    }
    __syncthreads();
    for (int n = threadIdx.x; n < nn; n += 256) {
        int ct = lrel[n * 3] + lrel[n * 3 + 1] + lrel[n * 3 + 2];
        int need = ((ct + 3) & ~3) - ct;          // 0..3 pads, w = 0
        int cur = lcnt[n];
        for (int k = 0; k < need; ++k) {
            uint2 z; z.x = 0u; z.y = 0u;
            edges2[cur + k] = z;
            edges1[cur + k] = 0u;        // w=0 -> contributes nothing
        }
    }
}

// ---------------------------------------------------------------------------
// K7: FUSED conv1 + gemm_Y. Block = 64 nodes, 512 threads (8 waves),
// LDS = Cs only (50 KB, 3 blocks/CU). Phases:
//  1. stream edges -> Cs count matrix (LDS f32 atomics, sparse bins)
//  2. AGG = C @ msg (MFMA K=192) + root1t, relu -> h1 tile into LDS
//     (h1s overlays dead Cs; 68-u16 row stride -> conflict-free phase-3 reads)
//  3. [16,64]@[64,256] MFMA from LDS: R = h1@root2+b2, Y_r = h1@W2_r -> global
// No h1 global round-trip; gemm_Y kernel eliminated.
// ---------------------------------------------------------------------------
#define CSTR 196
__global__ void __launch_bounds__(512) conv1_fused(
        const unsigned* __restrict__ edges1, const int* __restrict__ base1,
        const unsigned short* __restrict__ B1f, const float* __restrict__ root1t,
        const unsigned char* __restrict__ combo, const unsigned short* __restrict__ B2f,
        const float* __restrict__ b2, unsigned short* __restrict__ Rb,
        unsigned short* __restrict__ Y, int N) {
    __shared__ float Cs[64 * CSTR];
    unsigned short* h1s = (unsigned short*)Cs;   // [64][68] overlay (Cs dead by then)
    for (int t = threadIdx.x; t < 64 * CSTR; t += 512) Cs[t] = 0.f;
    __syncthreads();
    int g0 = blockIdx.x * 64;
    int gEnd = min(g0 + 64, N);
    int estart = base1[g0], eend = base1[gEnd];
    for (int e = estart + threadIdx.x; e < eend; e += 512) {
        unsigned ew = edges1[e];
        float wt = asf(ew & 0xFFFF0000u);        // bf16 weight in high bits
        atomicAdd(&Cs[((ew >> 8) & 63) * CSTR + (ew & 255u)], wt);
    }
    __syncthreads();
    int lane = threadIdx.x & 63;
    int w0 = threadIdx.x >> 6;          // 0..7
    int tile = w0 >> 1;                 // 16-node tile 0..3
    int node0 = g0 + 16 * tile;
    int m = lane & 15, kg = lane >> 4;
    // phase 2a: load count fragments (Cs still live)
    const float* cr = &Cs[(16 * tile + m) * CSTR];
    short8 a[6];
#pragma unroll
    for (int kt = 0; kt < 6; ++kt) {
        float4 ca = *(const float4*)(cr + kt * 32 + kg * 8);
        float4 cb = *(const float4*)(cr + kt * 32 + kg * 8 + 4);
        short8 av;
        av[0] = (short)f2bf(ca.x); av[1] = (short)f2bf(ca.y);
        av[2] = (short)f2bf(ca.z); av[3] = (short)f2bf(ca.w);
        av[4] = (short)f2bf(cb.x); av[5] = (short)f2bf(cb.y);
        av[6] = (short)f2bf(cb.z); av[7] = (short)f2bf(cb.w);
        a[kt] = av;
    }
    __syncthreads();    // all waves have their fragments; Cs is now dead
    // phase 2b: conv1 MFMA -> h1 tile into LDS (2 nt column-tiles per wave)
#pragma unroll
    for (int nt2 = 0; nt2 < 2; ++nt2) {
        int nt = (w0 & 1) * 2 + nt2;
        floatx4 c = {0.f, 0.f, 0.f, 0.f};
#pragma unroll
        for (int kt = 0; kt < 6; ++kt) {
            short8 b = *(const short8*)(B1f + ((nt * 6 + kt) * 64 + lane) * 8);
            c = __builtin_amdgcn_mfma_f32_16x16x32_bf16(a[kt], b, c, 0, 0, 0);
        }
#pragma unroll
        for (int q = 0; q < 4; ++q) {
            int node = node0 + kg * 4 + q;
            int cidx = combo[node < N ? node : N - 1];
            float v = c[q] + root1t[cidx * 64 + nt * 16 + m];
            v = v > 0.f ? v : 0.f;
            h1s[(16 * tile + kg * 4 + q) * 68 + nt * 16 + m] = (unsigned short)f2bf(v);
        }
    }
    __syncthreads();
    // phase 3: gemm_Y from LDS (each tile covered by 2 waves, 8 nt each)
    short8 a2[2];
#pragma unroll
    for (int kt = 0; kt < 2; ++kt)
        a2[kt] = *(const short8*)&h1s[(16 * tile + m) * 68 + kt * 32 + kg * 8];
#pragma unroll
    for (int nt2 = 0; nt2 < 8; ++nt2) {
        int nt = (w0 & 1) * 8 + nt2;
        floatx4 c = {0.f, 0.f, 0.f, 0.f};
#pragma unroll
        for (int kt = 0; kt < 2; ++kt) {
            short8 b = *(const short8*)(B2f + ((nt * 2 + kt) * 64 + lane) * 8);
            c = __builtin_amdgcn_mfma_f32_16x16x32_bf16(a2[kt], b, c, 0, 0, 0);
        }
        if (nt < 4) {
            int col = nt * 16 + m;
            float bias = b2[col];
#pragma unroll
            for (int q = 0; q < 4; ++q) {
                int node = node0 + kg * 4 + q;
                if (node < N) Rb[(size_t)node * 64 + col] = (unsigned short)f2bf(c[q] + bias);
            }
        } else {
            int r = (nt - 4) >> 2;
            int ycol = ((nt - 4) & 3) * 16 + m;
#pragma unroll
            for (int q = 0; q < 4; ++q) {
                int node = node0 + kg * 4 + q;
                if (node < N)
                    Y[((size_t)r * N + node) * 64 + ycol] = (unsigned short)f2bf(c[q]);
            }
        }
    }
}

// ---------------------------------------------------------------------------
// K9: conv2 gather, HALF-WAVE per node. 8 lanes x uint4 (16B) per edge ->
// 4 edges/iter per node; unroll x2. h2 = R + sum (pre-relu).
// ---------------------------------------------------------------------------
__global__ void __launch_bounds__(256) conv2_gather(
        const uint2* __restrict__ edges2, const int* __restrict__ base1,
        const unsigned short* __restrict__ plen, const uint4* __restrict__ Yu4,
        const uint4* __restrict__ Ru4, uint4* __restrict__ h2u4, int N) {
    int i = blockIdx.x * 8 + (threadIdx.x >> 5);   // node per 32-lane half
    if (i >= N) return;
    int l5 = threadIdx.x & 31;
    int el = l5 >> 3;        // edge slot 0..3
    int dl = l5 & 7;         // dim octet 0..7 (8 bf16 each)
    int s = base1[i];
    int L = plen[i];
    float f0 = 0.f, f1 = 0.f, f2 = 0.f, f3 = 0.f;
    float f4 = 0.f, f5 = 0.f, f6 = 0.f, f7 = 0.f;
    int t2 = 0;
    for (; t2 + 8 <= L; t2 += 8) {
        uint2 ea = edges2[s + t2 + el];
        uint2 eb = edges2[s + t2 + 4 + el];
        uint4 va = Yu4[(size_t)(ea.x >> 1) + dl];
        uint4 vb = Yu4[(size_t)(eb.x >> 1) + dl];
        float wa = asf(ea.y), wb = asf(eb.y);
        f0 = fmaf(wa, asf(va.x << 16), f0);
        f1 = fmaf(wa, asf(va.x & 0xFFFF0000u), f1);
        f2 = fmaf(wa, asf(va.y << 16), f2);
        f3 = fmaf(wa, asf(va.y & 0xFFFF0000u), f3);
        f4 = fmaf(wa, asf(va.z << 16), f4);
        f5 = fmaf(wa, asf(va.z & 0xFFFF0000u), f5);
        f6 = fmaf(wa, asf(va.w << 16), f6);
        f7 = fmaf(wa, asf(va.w & 0xFFFF0000u), f7);
        f0 = fmaf(wb, asf(vb.x << 16), f0);
        f1 = fmaf(wb, asf(vb.x & 0xFFFF0000u), f1);
        f2 = fmaf(wb, asf(vb.y << 16), f2);
        f3 = fmaf(wb, asf(vb.y & 0xFFFF0000u), f3);
        f4 = fmaf(wb, asf(vb.z << 16), f4);
        f5 = fmaf(wb, asf(vb.z & 0xFFFF0000u), f5);
        f6 = fmaf(wb, asf(vb.w << 16), f6);
        f7 = fmaf(wb, asf(vb.w & 0xFFFF0000u), f7);
    }
    if (t2 < L) {
        uint2 ea = edges2[s + t2 + el];
        uint4 va = Yu4[(size_t)(ea.x >> 1) + dl];
        float wa = asf(ea.y);
        f0 = fmaf(wa, asf(va.x << 16), f0);
        f1 = fmaf(wa, asf(va.x & 0xFFFF0000u), f1);
        f2 = fmaf(wa, asf(va.y << 16), f2);
        f3 = fmaf(wa, asf(va.y & 0xFFFF0000u), f3);
        f4 = fmaf(wa, asf(va.z << 16), f4);
        f5 = fmaf(wa, asf(va.z & 0xFFFF0000u), f5);
        f6 = fmaf(wa, asf(va.w << 16), f6);
        f7 = fmaf(wa, asf(va.w & 0xFFFF0000u), f7);
    }
    f0 += __shfl_xor(f0, 8); f0 += __shfl_xor(f0, 16);
    f1 += __shfl_xor(f1, 8); f1 += __shfl_xor(f1, 16);
    f2 += __shfl_xor(f2, 8); f2 += __shfl_xor(f2, 16);
    f3 += __shfl_xor(f3, 8); f3 += __shfl_xor(f3, 16);
    f4 += __shfl_xor(f4, 8); f4 += __shfl_xor(f4, 16);
    f5 += __shfl_xor(f5, 8); f5 += __shfl_xor(f5, 16);
    f6 += __shfl_xor(f6, 8); f6 += __shfl_xor(f6, 16);
    f7 += __shfl_xor(f7, 8); f7 += __shfl_xor(f7, 16);
    if (el == 0) {
        uint4 rb = Ru4[(size_t)i * 8 + dl];
        f0 += asf(rb.x << 16);
        f1 += asf(rb.x & 0xFFFF0000u);
        f2 += asf(rb.y << 16);
        f3 += asf(rb.y & 0xFFFF0000u);
        f4 += asf(rb.z << 16);
        f5 += asf(rb.z & 0xFFFF0000u);
        f6 += asf(rb.w << 16);
        f7 += asf(rb.w & 0xFFFF0000u);
        uint4 o;
        o.x = f2bf(f0) | (f2bf(f1) << 16);
        o.y = f2bf(f2) | (f2bf(f3) << 16);
        o.z = f2bf(f4) | (f2bf(f5) << 16);
        o.w = f2bf(f6) | (f2bf(f7) << 16);
        h2u4[(size_t)i * 8 + dl] = o;
    }
}

// ---------------------------------------------------------------------------
// K10: mean-pool + classifier, 4 waves per graph.
// ---------------------------------------------------------------------------
__global__ void __launch_bounds__(256) pool_cls(
        const unsigned short* __restrict__ h2, const int* __restrict__ batch,
        const float* __restrict__ cls_w, const float* __restrict__ cls_b,
        float* __restrict__ out, int N, int G) {
    int g = blockIdx.x;
    int lane = threadIdx.x & 63, w = threadIdx.x >> 6;
    auto lb = [&](int key) {
        int lo = 0, hi = N;
        while (lo < hi) { int mid = (lo + hi) >> 1; if (batch[mid] < key) lo = mid + 1; else hi = mid; }
        return lo;
    };
    int start = lb(g), end = lb(g + 1);
    float sum = 0.f;
    for (int i = start + w; i < end; i += 4) {
        float v = bf2f(h2[(size_t)i * 64 + lane]);
        sum += v > 0.f ? v : 0.f;
    }
    __shared__ float ps[4][64];
    ps[w][lane] = sum;
    __syncthreads();
    if (w == 0) {
        float tot = ps[0][lane] + ps[1][lane] + ps[2][lane] + ps[3][lane];
        int cntn = end - start;
        ps[0][lane] = tot / (float)(cntn > 0 ? cntn : 1);
    }
    __syncthreads();
    if (threadIdx.x < 10) {
        float o = cls_b[threadIdx.x];
#pragma unroll
        for (int j = 0; j < 64; ++j) o = fmaf(ps[0][j], cls_w[j * 10 + threadIdx.x], o);
        out[g * 10 + threadIdx.x] = o;
    }
}

// ---------------------------------------------------------------------------
extern "C" void kernel_launch(void* const* d_in, const int* in_sizes, int n_in,
                              void* d_out, int out_size, void* d_ws, size_t ws_size,
                              hipStream_t stream) {
    const int*   node_x = (const int*)d_in[0];
    const int*   ei     = (const int*)d_in[1];
    const int*   et     = (const int*)d_in[2];
    const int*   batch  = (const int*)d_in[3];
    const float* pre_w  = (const float*)d_in[4];
    const float* pre_b  = (const float*)d_in[5];
    const float* w1     = (const float*)d_in[6];
    const float* root1  = (const float*)d_in[7];
    const float* b1     = (const float*)d_in[8];
    const float* w2     = (const float*)d_in[9];
    const float* root2  = (const float*)d_in[10];
    const float* b2     = (const float*)d_in[11];
    const float* cls_w  = (const float*)d_in[12];
    const float* cls_b  = (const float*)d_in[13];
    float* out = (float*)d_out;

    int N = in_sizes[0] / 2;
    int E = in_sizes[1] / 2;
    int G = out_size / 10;

    int NB = (N + BNODES - 1) >> BSH;
    int chunk = (E + NBLK_A - 1) / NBLK_A;
    int nh = NB * NBLK_A;
    int nscan = (nh + 1023) / 1024;
    int EP = E + NB * BNODES * 3;      // whole-node pads (<=3/node)

    char* ws = (char*)d_ws;
    size_t off_b = 0;
    auto alloc = [&](size_t bytes) {
        void* p = ws + off_b;
        off_b = (off_b + bytes + 255) & ~(size_t)255;
        return p;
    };
    unsigned short* B1f    = (unsigned short*)alloc(4 * 6 * 64 * 8 * sizeof(short));
    float*          root1t = (float*)alloc(64 * 64 * sizeof(float));
    unsigned short* B2f    = (unsigned short*)alloc(16 * 2 * 64 * 8 * sizeof(short));
    unsigned char*  combo  = (unsigned char*)alloc((size_t)N + 64);
    int*            hist   = (int*)alloc((size_t)nh * sizeof(int));
    int*            hoff   = (int*)alloc((size_t)nh * sizeof(int));
    int*            bsums  = (int*)alloc(128 * sizeof(int));
    unsigned*       staged = (unsigned*)alloc((size_t)E * sizeof(unsigned));
    unsigned*       edges1 = (unsigned*)alloc((size_t)EP * sizeof(unsigned));
    uint2*          edges2 = (uint2*)alloc(((size_t)EP + 16) * sizeof(uint2));
    int*            base1  = (int*)alloc(((size_t)N + 8) * sizeof(int));
    unsigned short* plen   = (unsigned short*)alloc(((size_t)N + 8) * sizeof(short));
    unsigned short* Rb     = (unsigned short*)alloc((size_t)N * 64 * sizeof(short));
    unsigned short* Y      = (unsigned short*)alloc((size_t)3 * N * 64 * sizeof(short));
    unsigned short* h2     = (unsigned short*)alloc((size_t)N * 64 * sizeof(short));

    setup_kernel<<<64, 256, 0, stream>>>(pre_w, pre_b, w1, root1, b1, root2, w2,
                                         B1f, root1t, B2f);
    combo_kernel<<<(N + 255) / 256, 256, 0, stream>>>(node_x, combo, N);

    hist_kernel<<<NBLK_A, 256, 0, stream>>>(ei, hist, E, NB, chunk);
    scan1<<<nscan, 1024, 0, stream>>>(hist, hoff, bsums, nh);
    scan2<<<1, 128, 0, stream>>>(bsums, nscan);
    scan3<<<nscan, 1024, 0, stream>>>(hoff, bsums, nh);
    place_kernel<<<NBLK_A, 256, 0, stream>>>(ei, et, hoff, staged, E, NB, chunk);
    finalize_kernel<<<NB, 256, 0, stream>>>(staged, hoff, combo, edges1, edges2,
                                            base1, plen, E, N, NB);

    conv1_fused<<<(N + 63) / 64, 512, 0, stream>>>(edges1, base1, B1f, root1t, combo,
                                                   B2f, b2, Rb, Y, N);
    conv2_gather<<<(N + 7) / 8, 256, 0, stream>>>(edges2, base1, plen, (const uint4*)Y,
                                                  (const uint4*)Rb, (uint4*)h2, N);
    pool_cls<<<G, 256, 0, stream>>>(h2, batch, cls_w, cls_b, out, N, G);
}

// Round 19
// 157.263 us; speedup vs baseline: 7.1570x; 1.0154x over previous
//
#include <hip/hip_runtime.h>

#define BSH 9              // 512 nodes per dst bucket
#define BNODES 512
#define NBLK_A 256         // blocks in hist/place passes

typedef __attribute__((ext_vector_type(8))) short short8;
typedef __attribute__((ext_vector_type(4))) float floatx4;
typedef __attribute__((ext_vector_type(4))) int intx4;

static __device__ inline float bf2f(unsigned short u) {
    union { unsigned int i; float f; } v; v.i = ((unsigned int)u) << 16; return v.f;
}
static __device__ inline unsigned f2bf(float f) {
    union { float f; unsigned int i; } v; v.f = f;
    unsigned int x = v.i;
    return (x + 0x7FFF + ((x >> 16) & 1)) >> 16;  // RNE
}
static __device__ inline float asf(unsigned int u) {
    union { unsigned int i; float f; } v; v.i = u; return v.f;
}
static __device__ inline unsigned asu(float f) {
    union { float f; unsigned int i; } v; v.f = f; return v.i;
}

// ---------------------------------------------------------------------------
// K1 (merged setup): per-combo tables + B2 fragments.
// ---------------------------------------------------------------------------
__global__ void __launch_bounds__(256) setup_kernel(
        const float* __restrict__ pre_w, const float* __restrict__ pre_b,
        const float* __restrict__ w1, const float* __restrict__ root1,
        const float* __restrict__ b1, const float* __restrict__ root2,
        const float* __restrict__ w2,
        unsigned short* __restrict__ B1f, float* __restrict__ root1t,
        unsigned short* __restrict__ B2f) {
    int combo = blockIdx.x;
    int t = threadIdx.x;
    __shared__ float x1s[32];
    if (t < 32) {
        int s = combo >> 3, c = combo & 7;
        float v = pre_w[s * 32 + t] + pre_w[(8 + c) * 32 + t] + pre_b[t];
        x1s[t] = v > 0.f ? v : 0.f;
    }
    __syncthreads();
    if (t < 64) {
        int j = t;
        float acc = b1[j];
#pragma unroll
        for (int k = 0; k < 32; ++k) acc = fmaf(x1s[k], root1[k * 64 + j], acc);
        root1t[combo * 64 + j] = acc;
        for (int r = 0; r < 3; ++r) {
            float a = 0.f;
#pragma unroll
            for (int k = 0; k < 32; ++k) a = fmaf(x1s[k], w1[(r * 32 + k) * 64 + j], a);
            int idx = (r << 6) | combo;            // B row
            int kt = idx >> 5, i = idx & 7, lrow = (idx >> 3) & 3;
            int nt = j >> 4;
            int l = (lrow << 4) | (j & 15);
            B1f[(((nt * 6 + kt) * 64) + l) * 8 + i] = (unsigned short)f2bf(a);
        }
    }
    {   // B2f: [root2 | W2_0 | W2_1 | W2_2] fragments
        int tt = combo * 256 + t;                  // 0 .. 16383
        int i = tt & 7, l = (tt >> 3) & 63, kt = (tt >> 9) & 1, nt = tt >> 10;
        int k = kt * 32 + ((l >> 4) * 8) + i;
        int col = nt * 16 + (l & 15);
        float v;
        if (col < 64) v = root2[k * 64 + col];
        else {
            int r = (col - 64) >> 6, wcol = (col - 64) & 63;
            v = w2[(r * 64 + k) * 64 + wcol];
        }
        B2f[tt] = (unsigned short)f2bf(v);
    }
}

// K3: combo[i] as u8
__global__ void combo_kernel(const int* __restrict__ node_x, unsigned char* __restrict__ combo, int N) {
    int i = blockIdx.x * blockDim.x + threadIdx.x;
    if (i < N) combo[i] = (unsigned char)(node_x[2 * i] * 8 + node_x[2 * i + 1]);
}

// ---------------------------------------------------------------------------
// K4 (pass A0): per-block dst-bucket histogram. hist[b*NBLK_A + blk]
// ---------------------------------------------------------------------------
__global__ void __launch_bounds__(256) hist_kernel(const int* __restrict__ ei,
                                                   int* __restrict__ hist, int E, int NB, int chunk) {
    __shared__ int lh[256];
    for (int t = threadIdx.x; t < NB; t += 256) lh[t] = 0;
    __syncthreads();
    int s = blockIdx.x * chunk, e1 = min(E, s + chunk);
    for (int e = s + threadIdx.x; e < e1; e += 256)
        atomicAdd(&lh[ei[E + e] >> BSH], 1);
    __syncthreads();
    for (int b = threadIdx.x; b < NB; b += 256) hist[b * NBLK_A + blockIdx.x] = lh[b];
}

// generic exclusive scan (3 kernels)
__global__ void scan1(const int* __restrict__ in, int* __restrict__ out,
                      int* __restrict__ bsums, int n) {
    __shared__ int s[1024];
    int i = blockIdx.x * 1024 + threadIdx.x;
    int d = (i < n) ? in[i] : 0;
    s[threadIdx.x] = d;
    __syncthreads();
    for (int off = 1; off < 1024; off <<= 1) {
        int v = (threadIdx.x >= off) ? s[threadIdx.x - off] : 0;
        __syncthreads();
        s[threadIdx.x] += v;
        __syncthreads();
    }
    if (i < n) out[i] = s[threadIdx.x] - d;
    if (threadIdx.x == 1023) bsums[blockIdx.x] = s[1023];
}
__global__ void scan2(int* __restrict__ bsums, int nb) {
    __shared__ int s[128];
    int v = (threadIdx.x < nb) ? bsums[threadIdx.x] : 0;
    s[threadIdx.x] = v;
    __syncthreads();
    for (int off = 1; off < 128; off <<= 1) {
        int u = (threadIdx.x >= off) ? s[threadIdx.x - off] : 0;
        __syncthreads();
        s[threadIdx.x] += u;
        __syncthreads();
    }
    if (threadIdx.x < nb) bsums[threadIdx.x] = s[threadIdx.x] - v;
}
__global__ void scan3(int* __restrict__ out, const int* __restrict__ bsums, int n) {
    int i = blockIdx.x * 1024 + threadIdx.x;
    if (i < n) out[i] += bsums[blockIdx.x];
}

// ---------------------------------------------------------------------------
// K5 (pass A1): place edges into dst-buckets. staged = dloc<<19 | rel<<17 | src
// ---------------------------------------------------------------------------
__global__ void __launch_bounds__(256) place_kernel(const int* __restrict__ ei, const int* __restrict__ et,
                                                    const int* __restrict__ off, unsigned* __restrict__ staged,
                                                    int E, int NB, int chunk) {
    __shared__ int lh[256];
    for (int t = threadIdx.x; t < NB; t += 256) lh[t] = 0;
    __syncthreads();
    int s = blockIdx.x * chunk, e1 = min(E, s + chunk);
    for (int e = s + threadIdx.x; e < e1; e += 256) {
        int d = ei[E + e];
        int b = d >> BSH;
        int lr = atomicAdd(&lh[b], 1);
        int pos = off[b * NBLK_A + blockIdx.x] + lr;
        staged[pos] = ((unsigned)(d & (BNODES - 1)) << 19) | ((unsigned)et[e] << 17) | (unsigned)ei[e];
    }
}

// ---------------------------------------------------------------------------
// K6 (pass B): finalize into whole-node x4-padded CSR with per-edge
// precomputed weight w = 1/cnt(dst,rel).
//   edges2[e] = { (rel*N+src)*16 (uint2 row offset into Y), asu(w) }
//   edges1[e] = wfix<<14 | (node%64)<<8 | (rel*64+combo)   (pads: 0)
//     where wfix = round(w * 2^17)  (18-bit fixed point; bin sums <= 2^17)
// ---------------------------------------------------------------------------
__global__ void __launch_bounds__(256) finalize_kernel(
        const unsigned* __restrict__ staged, const int* __restrict__ off,
        const unsigned char* __restrict__ combo,
        unsigned* __restrict__ edges1, uint2* __restrict__ edges2,
        int* __restrict__ base1, unsigned short* __restrict__ plen,
        int E, int N, int NB) {
    __shared__ int lrel[BNODES * 3];   // per-(node,rel) counts (stay counts)
    __shared__ float lwf[BNODES * 3];  // 1/count
    __shared__ int lcnt[BNODES];       // placement cursors
    __shared__ int part[256];
    int blk = blockIdx.x;
    int d0 = blk * BNODES;
    int nn = min(BNODES, N - d0);
    int estart = off[blk * NBLK_A];
    int eend = (blk == NB - 1) ? E : off[(blk + 1) * NBLK_A];
    int ebase = estart + blk * (BNODES * 3);   // padded-capacity base
    for (int t = threadIdx.x; t < BNODES * 3; t += 256) lrel[t] = 0;
    __syncthreads();
    for (int e = estart + threadIdx.x; e < eend; e += 256) {
        unsigned p = staged[e];
        atomicAdd(&lrel[(p >> 19) * 3 + ((p >> 17) & 3)], 1);
    }
    __syncthreads();
    for (int j = threadIdx.x; j < BNODES * 3; j += 256) {
        int c = lrel[j];
        lwf[j] = c ? 1.f / (float)c : 0.f;
    }
    // padded exclusive scan over whole-node lengths (2 nodes/thread)
    int t = threadIdx.x;
    int n0 = 2 * t, n1 = 2 * t + 1;
    int ct0 = lrel[n0 * 3] + lrel[n0 * 3 + 1] + lrel[n0 * 3 + 2];
    int ct1 = lrel[n1 * 3] + lrel[n1 * 3 + 1] + lrel[n1 * 3 + 2];
    int pl0 = (ct0 + 3) & ~3, pl1 = (ct1 + 3) & ~3;
    int sum = pl0 + pl1;
    part[t] = sum;
    __syncthreads();
    for (int o = 1; o < 256; o <<= 1) {
        int u = (t >= o) ? part[t - o] : 0;
        __syncthreads();
        part[t] += u;
        __syncthreads();
    }
    int run = ebase + part[t] - sum;
    lcnt[n0] = run;
    lcnt[n1] = run + pl0;
    if (n0 < nn) { base1[d0 + n0] = run;       plen[d0 + n0] = (unsigned short)pl0; }
    if (n1 < nn) { base1[d0 + n1] = run + pl0; plen[d0 + n1] = (unsigned short)pl1; }
    if (blk == NB - 1 && t == 255) base1[N] = ebase + part[255];   // sentinel
    __syncthreads();
    for (int e = estart + threadIdx.x; e < eend; e += 256) {
        unsigned p = staged[e];
        int dloc = p >> 19;
        unsigned rel = (p >> 17) & 3;
        unsigned src = p & 0x1FFFF;
        float w = lwf[dloc * 3 + rel];
        unsigned wfix = (unsigned)(w * 131072.f + 0.5f);
        int slot = atomicAdd(&lcnt[dloc], 1);
        uint2 e2;
        e2.x = (rel * (unsigned)N + src) * 16u;
        e2.y = asu(w);
        edges2[slot] = e2;
        edges1[slot] = (wfix << 14) | ((unsigned)(dloc & 63) << 8)
                     | (rel << 6) | (unsigned)combo[src];
    }
    __syncthreads();
    for (int n = threadIdx.x; n < nn; n += 256) {
        int ct = lrel[n * 3] + lrel[n * 3 + 1] + lrel[n * 3 + 2];
        int need = ((ct + 3) & ~3) - ct;          // 0..3 pads, w = 0
        int cur = lcnt[n];
        for (int k = 0; k < need; ++k) {
            uint2 z; z.x = 0u; z.y = 0u;
            edges2[cur + k] = z;
            edges1[cur + k] = 0u;        // wfix=0 -> contributes nothing
        }
    }
}

// ---------------------------------------------------------------------------
// K7: FUSED conv1 + gemm_Y. Block = 64 nodes, 512 threads (8 waves).
// Edge range ends at base1[gLast] + plen[gLast] — NOT base1[g0+64], which
// on bucket boundaries includes uninitialized pad-capacity slack (the
// round-18 correctness bug). Phase 1 uses NATIVE int LDS atomics
// (fixed-point 2^-17 weights) instead of fp32 CAS loops.
// ---------------------------------------------------------------------------
#define CSTR 196
__global__ void __launch_bounds__(512) conv1_fused(
        const unsigned* __restrict__ edges1, const int* __restrict__ base1,
        const unsigned short* __restrict__ plen,
        const unsigned short* __restrict__ B1f, const float* __restrict__ root1t,
        const unsigned char* __restrict__ combo, const unsigned short* __restrict__ B2f,
        const float* __restrict__ b2, unsigned short* __restrict__ Rb,
        unsigned short* __restrict__ Y, int N) {
    __shared__ int Cs[64 * CSTR];
    __shared__ unsigned char comboS[64];
    unsigned short* h1s = (unsigned short*)Cs;   // [64][68] overlay (Cs dead by then)
    for (int t = threadIdx.x; t < 64 * CSTR; t += 512) Cs[t] = 0;
    int g0 = blockIdx.x * 64;
    int gLast = min(g0 + 63, N - 1);
    if (threadIdx.x < 64) {
        int node = g0 + threadIdx.x;
        comboS[threadIdx.x] = combo[node < N ? node : N - 1];
    }
    __syncthreads();
    int estart = base1[g0];
    int eend = base1[gLast] + plen[gLast];    // exact padded end of last node
    for (int e = estart + threadIdx.x; e < eend; e += 512) {
        unsigned ew = edges1[e];
        atomicAdd(&Cs[((ew >> 8) & 63) * CSTR + (ew & 255u)], (int)(ew >> 14));
    }
    __syncthreads();
    int lane = threadIdx.x & 63;
    int w0 = threadIdx.x >> 6;          // 0..7
    int tile = w0 >> 1;                 // 16-node tile 0..3
    int node0 = g0 + 16 * tile;
    int m = lane & 15, kg = lane >> 4;
    // phase 2a: load count fragments (Cs still live), fixed-point -> bf16
    const int* cr = &Cs[(16 * tile + m) * CSTR];
    const float sc17 = 1.f / 131072.f;
    short8 a[6];
#pragma unroll
    for (int kt = 0; kt < 6; ++kt) {
        intx4 ca = *(const intx4*)(cr + kt * 32 + kg * 8);
        intx4 cb = *(const intx4*)(cr + kt * 32 + kg * 8 + 4);
        short8 av;
        av[0] = (short)f2bf((float)ca[0] * sc17); av[1] = (short)f2bf((float)ca[1] * sc17);
        av[2] = (short)f2bf((float)ca[2] * sc17); av[3] = (short)f2bf((float)ca[3] * sc17);
        av[4] = (short)f2bf((float)cb[0] * sc17); av[5] = (short)f2bf((float)cb[1] * sc17);
        av[6] = (short)f2bf((float)cb[2] * sc17); av[7] = (short)f2bf((float)cb[3] * sc17);
        a[kt] = av;
    }
    __syncthreads();    // all waves have their fragments; Cs is now dead
    // phase 2b: conv1 MFMA -> h1 tile into LDS (2 nt column-tiles per wave)
#pragma unroll
    for (int nt2 = 0; nt2 < 2; ++nt2) {
        int nt = (w0 & 1) * 2 + nt2;
        floatx4 c = {0.f, 0.f, 0.f, 0.f};
#pragma unroll
        for (int kt = 0; kt < 6; ++kt) {
            short8 b = *(const short8*)(B1f + ((nt * 6 + kt) * 64 + lane) * 8);
            c = __builtin_amdgcn_mfma_f32_16x16x32_bf16(a[kt], b, c, 0, 0, 0);
        }
#pragma unroll
        for (int q = 0; q < 4; ++q) {
            int cidx = comboS[16 * tile + kg * 4 + q];
            float v = c[q] + root1t[cidx * 64 + nt * 16 + m];
            v = v > 0.f ? v : 0.f;
            h1s[(16 * tile + kg * 4 + q) * 68 + nt * 16 + m] = (unsigned short)f2bf(v);
        }
    }
    __syncthreads();
    // phase 3: gemm_Y from LDS (each tile covered by 2 waves, 8 nt each)
    short8 a2[2];
#pragma unroll
    for (int kt = 0; kt < 2; ++kt)
        a2[kt] = *(const short8*)&h1s[(16 * tile + m) * 68 + kt * 32 + kg * 8];
#pragma unroll
    for (int nt2 = 0; nt2 < 8; ++nt2) {
        int nt = (w0 & 1) * 8 + nt2;
        floatx4 c = {0.f, 0.f, 0.f, 0.f};
#pragma unroll
        for (int kt = 0; kt < 2; ++kt) {
            short8 b = *(const short8*)(B2f + ((nt * 2 + kt) * 64 + lane) * 8);
            c = __builtin_amdgcn_mfma_f32_16x16x32_bf16(a2[kt], b, c, 0, 0, 0);
        }
        if (nt < 4) {
            int col = nt * 16 + m;
            float bias = b2[col];
#pragma unroll
            for (int q = 0; q < 4; ++q) {
                int node = node0 + kg * 4 + q;
                if (node < N) Rb[(size_t)node * 64 + col] = (unsigned short)f2bf(c[q] + bias);
            }
        } else {
            int r = (nt - 4) >> 2;
            int ycol = ((nt - 4) & 3) * 16 + m;
#pragma unroll
            for (int q = 0; q < 4; ++q) {
                int node = node0 + kg * 4 + q;
                if (node < N)
                    Y[((size_t)r * N + node) * 64 + ycol] = (unsigned short)f2bf(c[q]);
            }
        }
    }
}

// ---------------------------------------------------------------------------
// K9: conv2 gather, HALF-WAVE per node. 8 lanes x uint4 (16B) per edge ->
// 4 edges/iter per node; unroll x2. h2 = R + sum (pre-relu).
// ---------------------------------------------------------------------------
__global__ void __launch_bounds__(256) conv2_gather(
        const uint2* __restrict__ edges2, const int* __restrict__ base1,
        const unsigned short* __restrict__ plen, const uint4* __restrict__ Yu4,
        const uint4* __restrict__ Ru4, uint4* __restrict__ h2u4, int N) {
    int i = blockIdx.x * 8 + (threadIdx.x >> 5);   // node per 32-lane half
    if (i >= N) return;
    int l5 = threadIdx.x & 31;
    int el = l5 >> 3;        // edge slot 0..3
    int dl = l5 & 7;         // dim octet 0..7 (8 bf16 each)
    int s = base1[i];
    int L = plen[i];
    float f0 = 0.f, f1 = 0.f, f2 = 0.f, f3 = 0.f;
    float f4 = 0.f, f5 = 0.f, f6 = 0.f, f7 = 0.f;
    int t2 = 0;
    for (; t2 + 8 <= L; t2 += 8) {
        uint2 ea = edges2[s + t2 + el];
        uint2 eb = edges2[s + t2 + 4 + el];
        uint4 va = Yu4[(size_t)(ea.x >> 1) + dl];
        uint4 vb = Yu4[(size_t)(eb.x >> 1) + dl];
        float wa = asf(ea.y), wb = asf(eb.y);
        f0 = fmaf(wa, asf(va.x << 16), f0);
        f1 = fmaf(wa, asf(va.x & 0xFFFF0000u), f1);
        f2 = fmaf(wa, asf(va.y << 16), f2);
        f3 = fmaf(wa, asf(va.y & 0xFFFF0000u), f3);
        f4 = fmaf(wa, asf(va.z << 16), f4);
        f5 = fmaf(wa, asf(va.z & 0xFFFF0000u), f5);
        f6 = fmaf(wa, asf(va.w << 16), f6);
        f7 = fmaf(wa, asf(va.w & 0xFFFF0000u), f7);
        f0 = fmaf(wb, asf(vb.x << 16), f0);
        f1 = fmaf(wb, asf(vb.x & 0xFFFF0000u), f1);
        f2 = fmaf(wb, asf(vb.y << 16), f2);
        f3 = fmaf(wb, asf(vb.y & 0xFFFF0000u), f3);
        f4 = fmaf(wb, asf(vb.z << 16), f4);
        f5 = fmaf(wb, asf(vb.z & 0xFFFF0000u), f5);
        f6 = fmaf(wb, asf(vb.w << 16), f6);
        f7 = fmaf(wb, asf(vb.w & 0xFFFF0000u), f7);
    }
    if (t2 < L) {
        uint2 ea = edges2[s + t2 + el];
        uint4 va = Yu4[(size_t)(ea.x >> 1) + dl];
        float wa = asf(ea.y);
        f0 = fmaf(wa, asf(va.x << 16), f0);
        f1 = fmaf(wa, asf(va.x & 0xFFFF0000u), f1);
        f2 = fmaf(wa, asf(va.y << 16), f2);
        f3 = fmaf(wa, asf(va.y & 0xFFFF0000u), f3);
        f4 = fmaf(wa, asf(va.z << 16), f4);
        f5 = fmaf(wa, asf(va.z & 0xFFFF0000u), f5);
        f6 = fmaf(wa, asf(va.w << 16), f6);
        f7 = fmaf(wa, asf(va.w & 0xFFFF0000u), f7);
    }
    f0 += __shfl_xor(f0, 8); f0 += __shfl_xor(f0, 16);
    f1 += __shfl_xor(f1, 8); f1 += __shfl_xor(f1, 16);
    f2 += __shfl_xor(f2, 8); f2 += __shfl_xor(f2, 16);
    f3 += __shfl_xor(f3, 8); f3 += __shfl_xor(f3, 16);
    f4 += __shfl_xor(f4, 8); f4 += __shfl_xor(f4, 16);
    f5 += __shfl_xor(f5, 8); f5 += __shfl_xor(f5, 16);
    f6 += __shfl_xor(f6, 8); f6 += __shfl_xor(f6, 16);
    f7 += __shfl_xor(f7, 8); f7 += __shfl_xor(f7, 16);
    if (el == 0) {
        uint4 rb = Ru4[(size_t)i * 8 + dl];
        f0 += asf(rb.x << 16);
        f1 += asf(rb.x & 0xFFFF0000u);
        f2 += asf(rb.y << 16);
        f3 += asf(rb.y & 0xFFFF0000u);
        f4 += asf(rb.z << 16);
        f5 += asf(rb.z & 0xFFFF0000u);
        f6 += asf(rb.w << 16);
        f7 += asf(rb.w & 0xFFFF0000u);
        uint4 o;
        o.x = f2bf(f0) | (f2bf(f1) << 16);
        o.y = f2bf(f2) | (f2bf(f3) << 16);
        o.z = f2bf(f4) | (f2bf(f5) << 16);
        o.w = f2bf(f6) | (f2bf(f7) << 16);
        h2u4[(size_t)i * 8 + dl] = o;
    }
}

// ---------------------------------------------------------------------------
// K10: mean-pool + classifier, 4 waves per graph.
// ---------------------------------------------------------------------------
__global__ void __launch_bounds__(256) pool_cls(
        const unsigned short* __restrict__ h2, const int* __restrict__ batch,
        const float* __restrict__ cls_w, const float* __restrict__ cls_b,
        float* __restrict__ out, int N, int G) {
    int g = blockIdx.x;
    int lane = threadIdx.x & 63, w = threadIdx.x >> 6;
    auto lb = [&](int key) {
        int lo = 0, hi = N;
        while (lo < hi) { int mid = (lo + hi) >> 1; if (batch[mid] < key) lo = mid + 1; else hi = mid; }
        return lo;
    };
    int start = lb(g), end = lb(g + 1);
    float sum = 0.f;
    for (int i = start + w; i < end; i += 4) {
        float v = bf2f(h2[(size_t)i * 64 + lane]);
        sum += v > 0.f ? v : 0.f;
    }
    __shared__ float ps[4][64];
    ps[w][lane] = sum;
    __syncthreads();
    if (w == 0) {
        float tot = ps[0][lane] + ps[1][lane] + ps[2][lane] + ps[3][lane];
        int cntn = end - start;
        ps[0][lane] = tot / (float)(cntn > 0 ? cntn : 1);
    }
    __syncthreads();
    if (threadIdx.x < 10) {
        float o = cls_b[threadIdx.x];
#pragma unroll
        for (int j = 0; j < 64; ++j) o = fmaf(ps[0][j], cls_w[j * 10 + threadIdx.x], o);
        out[g * 10 + threadIdx.x] = o;
    }
}

// ---------------------------------------------------------------------------
extern "C" void kernel_launch(void* const* d_in, const int* in_sizes, int n_in,
                              void* d_out, int out_size, void* d_ws, size_t ws_size,
                              hipStream_t stream) {
    const int*   node_x = (const int*)d_in[0];
    const int*   ei     = (const int*)d_in[1];
    const int*   et     = (const int*)d_in[2];
    const int*   batch  = (const int*)d_in[3];
    const float* pre_w  = (const float*)d_in[4];
    const float* pre_b  = (const float*)d_in[5];
    const float* w1     = (const float*)d_in[6];
    const float* root1  = (const float*)d_in[7];
    const float* b1     = (const float*)d_in[8];
    const float* w2     = (const float*)d_in[9];
    const float* root2  = (const float*)d_in[10];
    const float* b2     = (const float*)d_in[11];
    const float* cls_w  = (const float*)d_in[12];
    const float* cls_b  = (const float*)d_in[13];
    float* out = (float*)d_out;

    int N = in_sizes[0] / 2;
    int E = in_sizes[1] / 2;
    int G = out_size / 10;

    int NB = (N + BNODES - 1) >> BSH;
    int chunk = (E + NBLK_A - 1) / NBLK_A;
    int nh = NB * NBLK_A;
    int nscan = (nh + 1023) / 1024;
    int EP = E + NB * BNODES * 3;      // whole-node pads (<=3/node)

    char* ws = (char*)d_ws;
    size_t off_b = 0;
    auto alloc = [&](size_t bytes) {
        void* p = ws + off_b;
        off_b = (off_b + bytes + 255) & ~(size_t)255;
        return p;
    };
    unsigned short* B1f    = (unsigned short*)alloc(4 * 6 * 64 * 8 * sizeof(short));
    float*          root1t = (float*)alloc(64 * 64 * sizeof(float));
    unsigned short* B2f    = (unsigned short*)alloc(16 * 2 * 64 * 8 * sizeof(short));
    unsigned char*  combo  = (unsigned char*)alloc((size_t)N + 64);
    int*            hist   = (int*)alloc((size_t)nh * sizeof(int));
    int*            hoff   = (int*)alloc((size_t)nh * sizeof(int));
    int*            bsums  = (int*)alloc(128 * sizeof(int));
    unsigned*       staged = (unsigned*)alloc((size_t)E * sizeof(unsigned));
    unsigned*       edges1 = (unsigned*)alloc((size_t)EP * sizeof(unsigned));
    uint2*          edges2 = (uint2*)alloc(((size_t)EP + 16) * sizeof(uint2));
    int*            base1  = (int*)alloc(((size_t)N + 8) * sizeof(int));
    unsigned short* plen   = (unsigned short*)alloc(((size_t)N + 8) * sizeof(short));
    unsigned short* Rb     = (unsigned short*)alloc((size_t)N * 64 * sizeof(short));
    unsigned short* Y      = (unsigned short*)alloc((size_t)3 * N * 64 * sizeof(short));
    unsigned short* h2     = (unsigned short*)alloc((size_t)N * 64 * sizeof(short));

    setup_kernel<<<64, 256, 0, stream>>>(pre_w, pre_b, w1, root1, b1, root2, w2,
                                         B1f, root1t, B2f);
    combo_kernel<<<(N + 255) / 256, 256, 0, stream>>>(node_x, combo, N);

    hist_kernel<<<NBLK_A, 256, 0, stream>>>(ei, hist, E, NB, chunk);
    scan1<<<nscan, 1024, 0, stream>>>(hist, hoff, bsums, nh);
    scan2<<<1, 128, 0, stream>>>(bsums, nscan);
    scan3<<<nscan, 1024, 0, stream>>>(hoff, bsums, nh);
    place_kernel<<<NBLK_A, 256, 0, stream>>>(ei, et, hoff, staged, E, NB, chunk);
    finalize_kernel<<<NB, 256, 0, stream>>>(staged, hoff, combo, edges1, edges2,
                                            base1, plen, E, N, NB);

    conv1_fused<<<(N + 63) / 64, 512, 0, stream>>>(edges1, base1, plen, B1f, root1t,
                                                   combo, B2f, b2, Rb, Y, N);
    conv2_gather<<<(N + 7) / 8, 256, 0, stream>>>(edges2, base1, plen, (const uint4*)Y,
                                                  (const uint4*)Rb, (uint4*)h2, N);
    pool_cls<<<G, 256, 0, stream>>>(h2, batch, cls_w, cls_b, out, N, G);
}

// Round 20
// 155.884 us; speedup vs baseline: 7.2203x; 1.0088x over previous
//
#include <hip/hip_runtime.h>

#define BSH 9              // 512 nodes per dst bucket
#define BNODES 512
#define NBLK_A 256         // blocks in hist/place passes

typedef __attribute__((ext_vector_type(8))) short short8;
typedef __attribute__((ext_vector_type(4))) float floatx4;
typedef __attribute__((ext_vector_type(4))) int intx4;

static __device__ inline float bf2f(unsigned short u) {
    union { unsigned int i; float f; } v; v.i = ((unsigned int)u) << 16; return v.f;
}
static __device__ inline unsigned f2bf(float f) {
    union { float f; unsigned int i; } v; v.f = f;
    unsigned int x = v.i;
    return (x + 0x7FFF + ((x >> 16) & 1)) >> 16;  // RNE
}
static __device__ inline float asf(unsigned int u) {
    union { unsigned int i; float f; } v; v.i = u; return v.f;
}
static __device__ inline unsigned asu(float f) {
    union { float f; unsigned int i; } v; v.f = f; return v.i;
}

// ---------------------------------------------------------------------------
// K1 (merged setup): per-combo tables + B2 fragments.
// ---------------------------------------------------------------------------
__global__ void __launch_bounds__(256) setup_kernel(
        const float* __restrict__ pre_w, const float* __restrict__ pre_b,
        const float* __restrict__ w1, const float* __restrict__ root1,
        const float* __restrict__ b1, const float* __restrict__ root2,
        const float* __restrict__ w2,
        unsigned short* __restrict__ B1f, float* __restrict__ root1t,
        unsigned short* __restrict__ B2f) {
    int combo = blockIdx.x;
    int t = threadIdx.x;
    __shared__ float x1s[32];
    if (t < 32) {
        int s = combo >> 3, c = combo & 7;
        float v = pre_w[s * 32 + t] + pre_w[(8 + c) * 32 + t] + pre_b[t];
        x1s[t] = v > 0.f ? v : 0.f;
    }
    __syncthreads();
    if (t < 64) {
        int j = t;
        float acc = b1[j];
#pragma unroll
        for (int k = 0; k < 32; ++k) acc = fmaf(x1s[k], root1[k * 64 + j], acc);
        root1t[combo * 64 + j] = acc;
        for (int r = 0; r < 3; ++r) {
            float a = 0.f;
#pragma unroll
            for (int k = 0; k < 32; ++k) a = fmaf(x1s[k], w1[(r * 32 + k) * 64 + j], a);
            int idx = (r << 6) | combo;            // B row
            int kt = idx >> 5, i = idx & 7, lrow = (idx >> 3) & 3;
            int nt = j >> 4;
            int l = (lrow << 4) | (j & 15);
            B1f[(((nt * 6 + kt) * 64) + l) * 8 + i] = (unsigned short)f2bf(a);
        }
    }
    {   // B2f: [root2 | W2_0 | W2_1 | W2_2] fragments
        int tt = combo * 256 + t;                  // 0 .. 16383
        int i = tt & 7, l = (tt >> 3) & 63, kt = (tt >> 9) & 1, nt = tt >> 10;
        int k = kt * 32 + ((l >> 4) * 8) + i;
        int col = nt * 16 + (l & 15);
        float v;
        if (col < 64) v = root2[k * 64 + col];
        else {
            int r = (col - 64) >> 6, wcol = (col - 64) & 63;
            v = w2[(r * 64 + k) * 64 + wcol];
        }
        B2f[tt] = (unsigned short)f2bf(v);
    }
}

// K3: combo[i] as u8
__global__ void combo_kernel(const int* __restrict__ node_x, unsigned char* __restrict__ combo, int N) {
    int i = blockIdx.x * blockDim.x + threadIdx.x;
    if (i < N) combo[i] = (unsigned char)(node_x[2 * i] * 8 + node_x[2 * i + 1]);
}

// ---------------------------------------------------------------------------
// K4 (pass A0): per-block dst-bucket histogram. hist[b*NBLK_A + blk]
// ---------------------------------------------------------------------------
__global__ void __launch_bounds__(256) hist_kernel(const int* __restrict__ ei,
                                                   int* __restrict__ hist, int E, int NB, int chunk) {
    __shared__ int lh[256];
    for (int t = threadIdx.x; t < NB; t += 256) lh[t] = 0;
    __syncthreads();
    int s = blockIdx.x * chunk, e1 = min(E, s + chunk);
    for (int e = s + threadIdx.x; e < e1; e += 256)
        atomicAdd(&lh[ei[E + e] >> BSH], 1);
    __syncthreads();
    for (int b = threadIdx.x; b < NB; b += 256) hist[b * NBLK_A + blockIdx.x] = lh[b];
}

// generic exclusive scan (3 kernels)
__global__ void scan1(const int* __restrict__ in, int* __restrict__ out,
                      int* __restrict__ bsums, int n) {
    __shared__ int s[1024];
    int i = blockIdx.x * 1024 + threadIdx.x;
    int d = (i < n) ? in[i] : 0;
    s[threadIdx.x] = d;
    __syncthreads();
    for (int off = 1; off < 1024; off <<= 1) {
        int v = (threadIdx.x >= off) ? s[threadIdx.x - off] : 0;
        __syncthreads();
        s[threadIdx.x] += v;
        __syncthreads();
    }
    if (i < n) out[i] = s[threadIdx.x] - d;
    if (threadIdx.x == 1023) bsums[blockIdx.x] = s[1023];
}
__global__ void scan2(int* __restrict__ bsums, int nb) {
    __shared__ int s[128];
    int v = (threadIdx.x < nb) ? bsums[threadIdx.x] : 0;
    s[threadIdx.x] = v;
    __syncthreads();
    for (int off = 1; off < 128; off <<= 1) {
        int u = (threadIdx.x >= off) ? s[threadIdx.x - off] : 0;
        __syncthreads();
        s[threadIdx.x] += u;
        __syncthreads();
    }
    if (threadIdx.x < nb) bsums[threadIdx.x] = s[threadIdx.x] - v;
}
__global__ void scan3(int* __restrict__ out, const int* __restrict__ bsums, int n) {
    int i = blockIdx.x * 1024 + threadIdx.x;
    if (i < n) out[i] += bsums[blockIdx.x];
}

// ---------------------------------------------------------------------------
// K5 (pass A1): place edges into dst-buckets. staged = dloc<<19 | rel<<17 | src
// ---------------------------------------------------------------------------
__global__ void __launch_bounds__(256) place_kernel(const int* __restrict__ ei, const int* __restrict__ et,
                                                    const int* __restrict__ off, unsigned* __restrict__ staged,
                                                    int E, int NB, int chunk) {
    __shared__ int lh[256];
    for (int t = threadIdx.x; t < NB; t += 256) lh[t] = 0;
    __syncthreads();
    int s = blockIdx.x * chunk, e1 = min(E, s + chunk);
    for (int e = s + threadIdx.x; e < e1; e += 256) {
        int d = ei[E + e];
        int b = d >> BSH;
        int lr = atomicAdd(&lh[b], 1);
        int pos = off[b * NBLK_A + blockIdx.x] + lr;
        staged[pos] = ((unsigned)(d & (BNODES - 1)) << 19) | ((unsigned)et[e] << 17) | (unsigned)ei[e];
    }
}

// ---------------------------------------------------------------------------
// K6 (pass B): finalize into whole-node x4-padded CSR with per-edge
// precomputed weight w = 1/cnt(dst,rel).
//   edges2[e] = { (rel*N+src)*16 (uint2 row offset into Y), asu(w) }
//   edges1[e] = wfix<<14 | (node%64)<<8 | (rel*64+combo)   (pads: 0)
//     where wfix = round(w * 2^17)  (18-bit fixed point; bin sums <= 2^17)
// ---------------------------------------------------------------------------
__global__ void __launch_bounds__(256) finalize_kernel(
        const unsigned* __restrict__ staged, const int* __restrict__ off,
        const unsigned char* __restrict__ combo,
        unsigned* __restrict__ edges1, uint2* __restrict__ edges2,
        int* __restrict__ base1, unsigned short* __restrict__ plen,
        int E, int N, int NB) {
    __shared__ int lrel[BNODES * 3];   // per-(node,rel) counts (stay counts)
    __shared__ float lwf[BNODES * 3];  // 1/count
    __shared__ int lcnt[BNODES];       // placement cursors
    __shared__ int part[256];
    int blk = blockIdx.x;
    int d0 = blk * BNODES;
    int nn = min(BNODES, N - d0);
    int estart = off[blk * NBLK_A];
    int eend = (blk == NB - 1) ? E : off[(blk + 1) * NBLK_A];
    int ebase = estart + blk * (BNODES * 3);   // padded-capacity base
    for (int t = threadIdx.x; t < BNODES * 3; t += 256) lrel[t] = 0;
    __syncthreads();
    for (int e = estart + threadIdx.x; e < eend; e += 256) {
        unsigned p = staged[e];
        atomicAdd(&lrel[(p >> 19) * 3 + ((p >> 17) & 3)], 1);
    }
    __syncthreads();
    for (int j = threadIdx.x; j < BNODES * 3; j += 256) {
        int c = lrel[j];
        lwf[j] = c ? 1.f / (float)c : 0.f;
    }
    // padded exclusive scan over whole-node lengths (2 nodes/thread)
    int t = threadIdx.x;
    int n0 = 2 * t, n1 = 2 * t + 1;
    int ct0 = lrel[n0 * 3] + lrel[n0 * 3 + 1] + lrel[n0 * 3 + 2];
    int ct1 = lrel[n1 * 3] + lrel[n1 * 3 + 1] + lrel[n1 * 3 + 2];
    int pl0 = (ct0 + 3) & ~3, pl1 = (ct1 + 3) & ~3;
    int sum = pl0 + pl1;
    part[t] = sum;
    __syncthreads();
    for (int o = 1; o < 256; o <<= 1) {
        int u = (t >= o) ? part[t - o] : 0;
        __syncthreads();
        part[t] += u;
        __syncthreads();
    }
    int run = ebase + part[t] - sum;
    lcnt[n0] = run;
    lcnt[n1] = run + pl0;
    if (n0 < nn) { base1[d0 + n0] = run;       plen[d0 + n0] = (unsigned short)pl0; }
    if (n1 < nn) { base1[d0 + n1] = run + pl0; plen[d0 + n1] = (unsigned short)pl1; }
    if (blk == NB - 1 && t == 255) base1[N] = ebase + part[255];   // sentinel
    __syncthreads();
    for (int e = estart + threadIdx.x; e < eend; e += 256) {
        unsigned p = staged[e];
        int dloc = p >> 19;
        unsigned rel = (p >> 17) & 3;
        unsigned src = p & 0x1FFFF;
        float w = lwf[dloc * 3 + rel];
        unsigned wfix = (unsigned)(w * 131072.f + 0.5f);
        int slot = atomicAdd(&lcnt[dloc], 1);
        uint2 e2;
        e2.x = (rel * (unsigned)N + src) * 16u;
        e2.y = asu(w);
        edges2[slot] = e2;
        edges1[slot] = (wfix << 14) | ((unsigned)(dloc & 63) << 8)
                     | (rel << 6) | (unsigned)combo[src];
    }
    __syncthreads();
    for (int n = threadIdx.x; n < nn; n += 256) {
        int ct = lrel[n * 3] + lrel[n * 3 + 1] + lrel[n * 3 + 2];
        int need = ((ct + 3) & ~3) - ct;          // 0..3 pads, w = 0
        int cur = lcnt[n];
        for (int k = 0; k < need; ++k) {
            uint2 z; z.x = 0u; z.y = 0u;
            edges2[cur + k] = z;
            edges1[cur + k] = 0u;        // wfix=0 -> contributes nothing
        }
    }
}

// ---------------------------------------------------------------------------
// K7: FUSED conv1 + gemm_Y, 32-NODE blocks (25 KB LDS -> 4 blocks/CU, 32
// waves/CU occupancy ceiling vs 24 at 64-node/50 KB). 512 threads, 8 waves:
// 2 tiles x 4 waves. nl field masked &31 (g0 32-aligned so (node%64)&31 =
// node-g0). Edge range ends at base1[gLast]+plen[gLast] (exact padded end).
// ---------------------------------------------------------------------------
#define CSTR 196
__global__ void __launch_bounds__(512) conv1_fused(
        const unsigned* __restrict__ edges1, const int* __restrict__ base1,
        const unsigned short* __restrict__ plen,
        const unsigned short* __restrict__ B1f, const float* __restrict__ root1t,
        const unsigned char* __restrict__ combo, const unsigned short* __restrict__ B2f,
        const float* __restrict__ b2, unsigned short* __restrict__ Rb,
        unsigned short* __restrict__ Y, int N) {
    __shared__ int Cs[32 * CSTR];                // 25088 B
    __shared__ unsigned char comboS[32];
    unsigned short* h1s = (unsigned short*)Cs;   // [32][68] overlay (Cs dead by then)
    for (int t = threadIdx.x; t < 32 * CSTR; t += 512) Cs[t] = 0;
    int g0 = blockIdx.x * 32;
    int gLast = min(g0 + 31, N - 1);
    if (threadIdx.x < 32) {
        int node = g0 + threadIdx.x;
        comboS[threadIdx.x] = combo[node < N ? node : N - 1];
    }
    __syncthreads();
    int estart = base1[g0];
    int eend = base1[gLast] + plen[gLast];    // exact padded end of last node
    for (int e = estart + threadIdx.x; e < eend; e += 512) {
        unsigned ew = edges1[e];
        atomicAdd(&Cs[((ew >> 8) & 31) * CSTR + (ew & 255u)], (int)(ew >> 14));
    }
    __syncthreads();
    int lane = threadIdx.x & 63;
    int w0 = threadIdx.x >> 6;          // 0..7
    int tile = w0 >> 2;                 // 16-node tile 0..1
    int node0 = g0 + 16 * tile;
    int m = lane & 15, kg = lane >> 4;
    // phase 2a: load count fragments (Cs still live), fixed-point -> bf16
    const int* cr = &Cs[(16 * tile + m) * CSTR];
    const float sc17 = 1.f / 131072.f;
    short8 a[6];
#pragma unroll
    for (int kt = 0; kt < 6; ++kt) {
        intx4 ca = *(const intx4*)(cr + kt * 32 + kg * 8);
        intx4 cb = *(const intx4*)(cr + kt * 32 + kg * 8 + 4);
        short8 av;
        av[0] = (short)f2bf((float)ca[0] * sc17); av[1] = (short)f2bf((float)ca[1] * sc17);
        av[2] = (short)f2bf((float)ca[2] * sc17); av[3] = (short)f2bf((float)ca[3] * sc17);
        av[4] = (short)f2bf((float)cb[0] * sc17); av[5] = (short)f2bf((float)cb[1] * sc17);
        av[6] = (short)f2bf((float)cb[2] * sc17); av[7] = (short)f2bf((float)cb[3] * sc17);
        a[kt] = av;
    }
    __syncthreads();    // all waves have their fragments; Cs is now dead
    // phase 2b: conv1 MFMA -> h1 tile into LDS (1 nt column-tile per wave)
    {
        int nt = w0 & 3;
        floatx4 c = {0.f, 0.f, 0.f, 0.f};
#pragma unroll
        for (int kt = 0; kt < 6; ++kt) {
            short8 b = *(const short8*)(B1f + ((nt * 6 + kt) * 64 + lane) * 8);
            c = __builtin_amdgcn_mfma_f32_16x16x32_bf16(a[kt], b, c, 0, 0, 0);
        }
#pragma unroll
        for (int q = 0; q < 4; ++q) {
            int cidx = comboS[16 * tile + kg * 4 + q];
            float v = c[q] + root1t[cidx * 64 + nt * 16 + m];
            v = v > 0.f ? v : 0.f;
            h1s[(16 * tile + kg * 4 + q) * 68 + nt * 16 + m] = (unsigned short)f2bf(v);
        }
    }
    __syncthreads();
    // phase 3: gemm_Y from LDS (each tile covered by 4 waves, 4 nt each)
    short8 a2[2];
#pragma unroll
    for (int kt = 0; kt < 2; ++kt)
        a2[kt] = *(const short8*)&h1s[(16 * tile + m) * 68 + kt * 32 + kg * 8];
#pragma unroll
    for (int nt2 = 0; nt2 < 4; ++nt2) {
        int nt = (w0 & 3) * 4 + nt2;
        floatx4 c = {0.f, 0.f, 0.f, 0.f};
#pragma unroll
        for (int kt = 0; kt < 2; ++kt) {
            short8 b = *(const short8*)(B2f + ((nt * 2 + kt) * 64 + lane) * 8);
            c = __builtin_amdgcn_mfma_f32_16x16x32_bf16(a2[kt], b, c, 0, 0, 0);
        }
        if (nt < 4) {
            int col = nt * 16 + m;
            float bias = b2[col];
#pragma unroll
            for (int q = 0; q < 4; ++q) {
                int node = node0 + kg * 4 + q;
                if (node < N) Rb[(size_t)node * 64 + col] = (unsigned short)f2bf(c[q] + bias);
            }
        } else {
            int r = (nt - 4) >> 2;
            int ycol = ((nt - 4) & 3) * 16 + m;
#pragma unroll
            for (int q = 0; q < 4; ++q) {
                int node = node0 + kg * 4 + q;
                if (node < N)
                    Y[((size_t)r * N + node) * 64 + ycol] = (unsigned short)f2bf(c[q]);
            }
        }
    }
}

// ---------------------------------------------------------------------------
// K9: conv2 gather, HALF-WAVE per node. 8 lanes x uint4 (16B) per edge ->
// 4 edges/iter per node; unroll x2. h2 = R + sum (pre-relu).
// ---------------------------------------------------------------------------
__global__ void __launch_bounds__(256) conv2_gather(
        const uint2* __restrict__ edges2, const int* __restrict__ base1,
        const unsigned short* __restrict__ plen, const uint4* __restrict__ Yu4,
        const uint4* __restrict__ Ru4, uint4* __restrict__ h2u4, int N) {
    int i = blockIdx.x * 8 + (threadIdx.x >> 5);   // node per 32-lane half
    if (i >= N) return;
    int l5 = threadIdx.x & 31;
    int el = l5 >> 3;        // edge slot 0..3
    int dl = l5 & 7;         // dim octet 0..7 (8 bf16 each)
    int s = base1[i];
    int L = plen[i];
    float f0 = 0.f, f1 = 0.f, f2 = 0.f, f3 = 0.f;
    float f4 = 0.f, f5 = 0.f, f6 = 0.f, f7 = 0.f;
    int t2 = 0;
    for (; t2 + 8 <= L; t2 += 8) {
        uint2 ea = edges2[s + t2 + el];
        uint2 eb = edges2[s + t2 + 4 + el];
        uint4 va = Yu4[(size_t)(ea.x >> 1) + dl];
        uint4 vb = Yu4[(size_t)(eb.x >> 1) + dl];
        float wa = asf(ea.y), wb = asf(eb.y);
        f0 = fmaf(wa, asf(va.x << 16), f0);
        f1 = fmaf(wa, asf(va.x & 0xFFFF0000u), f1);
        f2 = fmaf(wa, asf(va.y << 16), f2);
        f3 = fmaf(wa, asf(va.y & 0xFFFF0000u), f3);
        f4 = fmaf(wa, asf(va.z << 16), f4);
        f5 = fmaf(wa, asf(va.z & 0xFFFF0000u), f5);
        f6 = fmaf(wa, asf(va.w << 16), f6);
        f7 = fmaf(wa, asf(va.w & 0xFFFF0000u), f7);
        f0 = fmaf(wb, asf(vb.x << 16), f0);
        f1 = fmaf(wb, asf(vb.x & 0xFFFF0000u), f1);
        f2 = fmaf(wb, asf(vb.y << 16), f2);
        f3 = fmaf(wb, asf(vb.y & 0xFFFF0000u), f3);
        f4 = fmaf(wb, asf(vb.z << 16), f4);
        f5 = fmaf(wb, asf(vb.z & 0xFFFF0000u), f5);
        f6 = fmaf(wb, asf(vb.w << 16), f6);
        f7 = fmaf(wb, asf(vb.w & 0xFFFF0000u), f7);
    }
    if (t2 < L) {
        uint2 ea = edges2[s + t2 + el];
        uint4 va = Yu4[(size_t)(ea.x >> 1) + dl];
        float wa = asf(ea.y);
        f0 = fmaf(wa, asf(va.x << 16), f0);
        f1 = fmaf(wa, asf(va.x & 0xFFFF0000u), f1);
        f2 = fmaf(wa, asf(va.y << 16), f2);
        f3 = fmaf(wa, asf(va.y & 0xFFFF0000u), f3);
        f4 = fmaf(wa, asf(va.z << 16), f4);
        f5 = fmaf(wa, asf(va.z & 0xFFFF0000u), f5);
        f6 = fmaf(wa, asf(va.w << 16), f6);
        f7 = fmaf(wa, asf(va.w & 0xFFFF0000u), f7);
    }
    f0 += __shfl_xor(f0, 8); f0 += __shfl_xor(f0, 16);
    f1 += __shfl_xor(f1, 8); f1 += __shfl_xor(f1, 16);
    f2 += __shfl_xor(f2, 8); f2 += __shfl_xor(f2, 16);
    f3 += __shfl_xor(f3, 8); f3 += __shfl_xor(f3, 16);
    f4 += __shfl_xor(f4, 8); f4 += __shfl_xor(f4, 16);
    f5 += __shfl_xor(f5, 8); f5 += __shfl_xor(f5, 16);
    f6 += __shfl_xor(f6, 8); f6 += __shfl_xor(f6, 16);
    f7 += __shfl_xor(f7, 8); f7 += __shfl_xor(f7, 16);
    if (el == 0) {
        uint4 rb = Ru4[(size_t)i * 8 + dl];
        f0 += asf(rb.x << 16);
        f1 += asf(rb.x & 0xFFFF0000u);
        f2 += asf(rb.y << 16);
        f3 += asf(rb.y & 0xFFFF0000u);
        f4 += asf(rb.z << 16);
        f5 += asf(rb.z & 0xFFFF0000u);
        f6 += asf(rb.w << 16);
        f7 += asf(rb.w & 0xFFFF0000u);
        uint4 o;
        o.x = f2bf(f0) | (f2bf(f1) << 16);
        o.y = f2bf(f2) | (f2bf(f3) << 16);
        o.z = f2bf(f4) | (f2bf(f5) << 16);
        o.w = f2bf(f6) | (f2bf(f7) << 16);
        h2u4[(size_t)i * 8 + dl] = o;
    }
}

// ---------------------------------------------------------------------------
// K10: mean-pool + classifier, 4 waves per graph.
// ---------------------------------------------------------------------------
__global__ void __launch_bounds__(256) pool_cls(
        const unsigned short* __restrict__ h2, const int* __restrict__ batch,
        const float* __restrict__ cls_w, const float* __restrict__ cls_b,
        float* __restrict__ out, int N, int G) {
    int g = blockIdx.x;
    int lane = threadIdx.x & 63, w = threadIdx.x >> 6;
    auto lb = [&](int key) {
        int lo = 0, hi = N;
        while (lo < hi) { int mid = (lo + hi) >> 1; if (batch[mid] < key) lo = mid + 1; else hi = mid; }
        return lo;
    };
    int start = lb(g), end = lb(g + 1);
    float sum = 0.f;
    for (int i = start + w; i < end; i += 4) {
        float v = bf2f(h2[(size_t)i * 64 + lane]);
        sum += v > 0.f ? v : 0.f;
    }
    __shared__ float ps[4][64];
    ps[w][lane] = sum;
    __syncthreads();
    if (w == 0) {
        float tot = ps[0][lane] + ps[1][lane] + ps[2][lane] + ps[3][lane];
        int cntn = end - start;
        ps[0][lane] = tot / (float)(cntn > 0 ? cntn : 1);
    }
    __syncthreads();
    if (threadIdx.x < 10) {
        float o = cls_b[threadIdx.x];
#pragma unroll
        for (int j = 0; j < 64; ++j) o = fmaf(ps[0][j], cls_w[j * 10 + threadIdx.x], o);
        out[g * 10 + threadIdx.x] = o;
    }
}

// ---------------------------------------------------------------------------
extern "C" void kernel_launch(void* const* d_in, const int* in_sizes, int n_in,
                              void* d_out, int out_size, void* d_ws, size_t ws_size,
                              hipStream_t stream) {
    const int*   node_x = (const int*)d_in[0];
    const int*   ei     = (const int*)d_in[1];
    const int*   et     = (const int*)d_in[2];
    const int*   batch  = (const int*)d_in[3];
    const float* pre_w  = (const float*)d_in[4];
    const float* pre_b  = (const float*)d_in[5];
    const float* w1     = (const float*)d_in[6];
    const float* root1  = (const float*)d_in[7];
    const float* b1     = (const float*)d_in[8];
    const float* w2     = (const float*)d_in[9];
    const float* root2  = (const float*)d_in[10];
    const float* b2     = (const float*)d_in[11];
    const float* cls_w  = (const float*)d_in[12];
    const float* cls_b  = (const float*)d_in[13];
    float* out = (float*)d_out;

    int N = in_sizes[0] / 2;
    int E = in_sizes[1] / 2;
    int G = out_size / 10;

    int NB = (N + BNODES - 1) >> BSH;
    int chunk = (E + NBLK_A - 1) / NBLK_A;
    int nh = NB * NBLK_A;
    int nscan = (nh + 1023) / 1024;
    int EP = E + NB * BNODES * 3;      // whole-node pads (<=3/node)

    char* ws = (char*)d_ws;
    size_t off_b = 0;
    auto alloc = [&](size_t bytes) {
        void* p = ws + off_b;
        off_b = (off_b + bytes + 255) & ~(size_t)255;
        return p;
    };
    unsigned short* B1f    = (unsigned short*)alloc(4 * 6 * 64 * 8 * sizeof(short));
    float*          root1t = (float*)alloc(64 * 64 * sizeof(float));
    unsigned short* B2f    = (unsigned short*)alloc(16 * 2 * 64 * 8 * sizeof(short));
    unsigned char*  combo  = (unsigned char*)alloc((size_t)N + 64);
    int*            hist   = (int*)alloc((size_t)nh * sizeof(int));
    int*            hoff   = (int*)alloc((size_t)nh * sizeof(int));
    int*            bsums  = (int*)alloc(128 * sizeof(int));
    unsigned*       staged = (unsigned*)alloc((size_t)E * sizeof(unsigned));
    unsigned*       edges1 = (unsigned*)alloc((size_t)EP * sizeof(unsigned));
    uint2*          edges2 = (uint2*)alloc(((size_t)EP + 16) * sizeof(uint2));
    int*            base1  = (int*)alloc(((size_t)N + 8) * sizeof(int));
    unsigned short* plen   = (unsigned short*)alloc(((size_t)N + 8) * sizeof(short));
    unsigned short* Rb     = (unsigned short*)alloc((size_t)N * 64 * sizeof(short));
    unsigned short* Y      = (unsigned short*)alloc((size_t)3 * N * 64 * sizeof(short));
    unsigned short* h2     = (unsigned short*)alloc((size_t)N * 64 * sizeof(short));

    setup_kernel<<<64, 256, 0, stream>>>(pre_w, pre_b, w1, root1, b1, root2, w2,
                                         B1f, root1t, B2f);
    combo_kernel<<<(N + 255) / 256, 256, 0, stream>>>(node_x, combo, N);

    hist_kernel<<<NBLK_A, 256, 0, stream>>>(ei, hist, E, NB, chunk);
    scan1<<<nscan, 1024, 0, stream>>>(hist, hoff, bsums, nh);
    scan2<<<1, 128, 0, stream>>>(bsums, nscan);
    scan3<<<nscan, 1024, 0, stream>>>(hoff, bsums, nh);
    place_kernel<<<NBLK_A, 256, 0, stream>>>(ei, et, hoff, staged, E, NB, chunk);
    finalize_kernel<<<NB, 256, 0, stream>>>(staged, hoff, combo, edges1, edges2,
                                            base1, plen, E, N, NB);

    conv1_fused<<<(N + 31) / 32, 512, 0, stream>>>(edges1, base1, plen, B1f, root1t,
                                                   combo, B2f, b2, Rb, Y, N);
    conv2_gather<<<(N + 7) / 8, 256, 0, stream>>>(edges2, base1, plen, (const uint4*)Y,
                                                  (const uint4*)Rb, (uint4*)h2, N);
    pool_cls<<<G, 256, 0, stream>>>(h2, batch, cls_w, cls_b, out, N, G);
}